// Round 2
// baseline (3143.120 us; speedup 1.0000x reference)
//
#include <hip/hip_runtime.h>

#define N_NODES 50000
#define N_EDGES 250000
#define DIM 300
#define DIM2 600
#define NL 5
#define MPAD 50048      // 391 * 128
#define KP1 320         // DIM padded to mult of 32
#define KP2 608         // DIM2 padded to mult of 32
#define NP1 640         // DIM2 padded to mult of 128
#define NP2 384         // DIM padded to mult of 128
#define SCAN_BLOCKS 196 // ceil(N_NODES / 256)
#define CT_STRIDE 136   // 128 + 8 pad: breaks epilogue LDS write conflicts

typedef __attribute__((ext_vector_type(8))) _Float16 half8;
typedef __attribute__((ext_vector_type(2))) _Float16 half2v;
typedef __attribute__((ext_vector_type(8))) short short8;
typedef __attribute__((ext_vector_type(4))) float f32x4;
typedef unsigned short ushort;
typedef unsigned int uint;

#define AS1 __attribute__((address_space(1)))
#define AS3 __attribute__((address_space(3)))

static __device__ __forceinline__ ushort f2h(float f) {
    _Float16 h = (_Float16)f;
    return __builtin_bit_cast(ushort, h);
}
static __device__ __forceinline__ float h2f(ushort s) {
    return (float)__builtin_bit_cast(_Float16, s);
}
static __device__ __forceinline__ uint pk2(float a, float b) {
    return (uint)f2h(a) | ((uint)f2h(b) << 16);
}
static __device__ __forceinline__ half2v u2h2(uint u) {
    return __builtin_bit_cast(half2v, u);
}

// bijective XCD-contiguous remap (m204): hardware assigns block o -> XCD o%8;
// give each XCD a contiguous run of logical tiles so an m-band's n-tiles share L2.
static __device__ __forceinline__ int xcd_swizzle(int o, int nwg) {
    int q = nwg >> 3, r = nwg & 7;
    int xcd = o & 7, idx = o >> 3;
    return (xcd < r ? xcd * (q + 1) : r * (q + 1) + (xcd - r) * q) + idx;
}

// ---------------- Atom encoder -> h fp16 ----------------
__global__ void atom_enc(const int* __restrict__ x, const float* __restrict__ emb,
                         ushort* __restrict__ h) {
    int idx = blockIdx.x * blockDim.x + threadIdx.x;  // pair index
    const int PAIRS = DIM / 2;  // 150
    if (idx >= N_NODES * PAIRS) return;
    int n = idx / PAIRS, p = idx - n * PAIRS;
    const int* xr = x + n * 9;
    float s0 = 0.f, s1 = 0.f;
#pragma unroll
    for (int i = 0; i < 9; i++) {
        const float2 v = *(const float2*)(emb + (size_t)(i * 128 + xr[i]) * DIM + 2 * p);
        s0 += v.x; s1 += v.y;
    }
    ((uint*)h)[idx] = pk2(s0, s1);
}

// ---------------- CSR build (once per launch; edge_index is layer-invariant) ----------
__global__ void deg_count(const int* __restrict__ ei, int* __restrict__ deg) {
    int e = blockIdx.x * blockDim.x + threadIdx.x;
    if (e < N_EDGES) atomicAdd(&deg[ei[N_EDGES + e]], 1);
}

__global__ void block_sums(const int* __restrict__ deg, int* __restrict__ bsum) {
    __shared__ int red[256];
    int tid = threadIdx.x;
    int node = blockIdx.x * 256 + tid;
    red[tid] = (node < N_NODES) ? deg[node] : 0;
    __syncthreads();
    for (int off = 128; off > 0; off >>= 1) {
        if (tid < off) red[tid] += red[tid + off];
        __syncthreads();
    }
    if (tid == 0) bsum[blockIdx.x] = red[0];
}

__global__ void scan_bsums(int* __restrict__ bsum) {
    __shared__ int s[256];
    int tid = threadIdx.x;
    int orig = (tid < SCAN_BLOCKS) ? bsum[tid] : 0;
    s[tid] = orig;
    __syncthreads();
    for (int off = 1; off < 256; off <<= 1) {
        int v = (tid >= off) ? s[tid - off] : 0;
        __syncthreads();
        s[tid] += v;
        __syncthreads();
    }
    if (tid < SCAN_BLOCKS) bsum[tid] = s[tid] - orig;  // exclusive
}

__global__ void write_rowstart(const int* __restrict__ deg, const int* __restrict__ bsum,
                               int* __restrict__ rowstart, int* __restrict__ cursor) {
    __shared__ int s[256];
    int tid = threadIdx.x;
    int node = blockIdx.x * 256 + tid;
    int d = (node < N_NODES) ? deg[node] : 0;
    s[tid] = d;
    __syncthreads();
    for (int off = 1; off < 256; off <<= 1) {
        int v = (tid >= off) ? s[tid - off] : 0;
        __syncthreads();
        s[tid] += v;
        __syncthreads();
    }
    int excl = s[tid] - d + bsum[blockIdx.x];
    if (node < N_NODES) {
        rowstart[node] = excl;
        cursor[node] = excl;
    }
    if (blockIdx.x == 0 && tid == 0) rowstart[N_NODES] = N_EDGES;
}

// fill CSR with pre-packed edge payload: (src, a0|a1<<8|a2<<16)
__global__ void csr_fill(const int* __restrict__ ei, const int* __restrict__ ea,
                         int* __restrict__ cursor, int2* __restrict__ epack) {
    int e = blockIdx.x * blockDim.x + threadIdx.x;
    if (e < N_EDGES) {
        int d = ei[N_EDGES + e];
        int slot = atomicAdd(&cursor[d], 1);
        int attr = ea[3 * e] | (ea[3 * e + 1] << 8) | (ea[3 * e + 2] << 16);
        epack[slot] = make_int2(ei[e], attr);
    }
}

// ---------------- per-layer bond table fp32 -> fp16 (28.8 KB, L1-resident) ----------
__global__ void bond_conv(const float* __restrict__ bond, ushort* __restrict__ bondh) {
    int idx = blockIdx.x * blockDim.x + threadIdx.x;  // pair index
    if (idx >= 48 * (DIM / 2)) return;
    float2 v = *(const float2*)(bond + 2 * idx);
    ((uint*)bondh)[idx] = pk2(v.x, v.y);
}

// ---------------- identity BN params for layer 0 ----------------
__global__ void init_bn(float* __restrict__ scale, float* __restrict__ shift) {
    int i = blockIdx.x * blockDim.x + threadIdx.x;
    if (i < DIM) { scale[i] = 1.f; shift[i] = 0.f; }
}

// ------- Fused BN2(+ReLU) on-load + gather-aggregate + GIN combine + fp16 cast --------
__launch_bounds__(256)
__global__ void agg_combine(const int* __restrict__ rowstart, const int2* __restrict__ epack,
                            const ushort* __restrict__ bondh, const ushort* __restrict__ h,
                            const float* __restrict__ scale, const float* __restrict__ shift,
                            int relu, const float* __restrict__ epsp, int layer,
                            ushort* __restrict__ A1) {
    int node = blockIdx.x * 4 + (threadIdx.x >> 6);
    int lane = threadIdx.x & 63;
    if (node >= MPAD) return;
    uint* row32 = (uint*)(A1 + (size_t)node * KP1);
    if (node >= N_NODES) {
        for (int i = lane; i < KP1 / 2; i += 64) row32[i] = 0;
        return;
    }
    const int PAIRS = DIM / 2;  // 150
    float2 scf[3], shf[3];
    half2v sch[3], shh[3];
#pragma unroll
    for (int i = 0; i < 3; i++) {
        int p = lane + 64 * i;
        scf[i] = make_float2(0.f, 0.f);
        shf[i] = make_float2(0.f, 0.f);
        if (p < PAIRS) {
            scf[i] = *(const float2*)(scale + 2 * p);
            shf[i] = *(const float2*)(shift + 2 * p);
        }
        sch[i] = half2v{(_Float16)scf[i].x, (_Float16)scf[i].y};
        shh[i] = half2v{(_Float16)shf[i].x, (_Float16)shf[i].y};
    }
    float epsv = 1.0f + epsp[layer];
    const uint* hd = (const uint*)(h + (size_t)node * DIM);
    float ax[3], ay[3];
#pragma unroll
    for (int i = 0; i < 3; i++) {
        int p = lane + 64 * i;
        ax[i] = 0.f; ay[i] = 0.f;
        if (p < PAIRS) {
            uint u = hd[p];
            float vx = h2f((ushort)(u & 0xffffu)) * scf[i].x + shf[i].x;
            float vy = h2f((ushort)(u >> 16)) * scf[i].y + shf[i].y;
            if (relu) { vx = fmaxf(vx, 0.f); vy = fmaxf(vy, 0.f); }
            ax[i] = epsv * vx; ay[i] = epsv * vy;
        }
    }

    auto edge_contrib = [&](int2 pk) {
        const uint* hs = (const uint*)(h + (size_t)pk.x * DIM);
        int a0 = pk.y & 0xff, a1v = (pk.y >> 8) & 0xff, a2 = (pk.y >> 16) & 0xff;
        const uint* t0 = (const uint*)(bondh + a0 * DIM);
        const uint* t1 = (const uint*)(bondh + (16 + a1v) * DIM);
        const uint* t2 = (const uint*)(bondh + (32 + a2) * DIM);
        const half2v z = {};
#pragma unroll
        for (int i = 0; i < 3; i++) {
            int p = lane + 64 * i;
            if (p < PAIRS) {
                half2v hv = u2h2(hs[p]) * sch[i] + shh[i];
                if (relu) hv = __builtin_elementwise_max(hv, z);
                half2v m = hv + u2h2(t0[p]) + u2h2(t1[p]) + u2h2(t2[p]);
                m = __builtin_elementwise_max(m, z);
                ax[i] += (float)m.x;
                ay[i] += (float)m.y;
            }
        }
    };

    int e0 = rowstart[node], e1 = rowstart[node + 1];
    int t = e0;
    for (; t + 1 < e1; t += 2) {
        int2 p0 = epack[t];
        int2 p1 = epack[t + 1];
        edge_contrib(p0);
        edge_contrib(p1);
    }
    if (t < e1) edge_contrib(epack[t]);

#pragma unroll
    for (int i = 0; i < 3; i++) {
        int p = lane + 64 * i;
        if (p < KP1 / 2) row32[p] = (p < PAIRS) ? pk2(ax[i], ay[i]) : 0u;
    }
}

// ---------------- W1 (K x N) -> Wt fp16 [NP x KP] transposed, zero-padded ----------
__global__ void wt_conv(const float* __restrict__ W, ushort* __restrict__ Wt,
                        int K, int Nc, int KP, int NP) {
    int idx = blockIdx.x * blockDim.x + threadIdx.x;
    if (idx >= KP * NP) return;
    int k = idx / NP, n = idx - k * NP;
    ushort v = 0;
    if (k < K && n < Nc) v = f2h(W[(size_t)k * Nc + n]);
    Wt[(size_t)n * KP + k] = v;
}

// ------- W2 with BN1 scale folded: Wt2[n][k] = fp16(scale1[k] * W2[k][n]) -------------
__global__ void wt_conv2(const float* __restrict__ W, const float* __restrict__ scale,
                         ushort* __restrict__ Wt) {
    int idx = blockIdx.x * blockDim.x + threadIdx.x;
    if (idx >= KP2 * NP2) return;
    int k = idx / NP2, n = idx - k * NP2;
    ushort v = 0;
    if (k < DIM2 && n < DIM) v = f2h(scale[k] * W[(size_t)k * DIM + n]);
    Wt[(size_t)n * KP2 + k] = v;
}

// ---------------- GEMM1: yh = A1 @ Wt1^T + b1, fp16 out + BN stats --------------------
// Occupancy-first structure: single-buffered 2-phase K-loop (inter-block TLP hides
// the staging drain at 6 blocks/CU), chunk-XOR LDS swizzle (conflict-free ds_read_b128),
// 64-row half-tile C epilogue. LDS ~18.4 KB -> 6 blocks/CU (capacity 1536 blocks).
__launch_bounds__(256, 6)
__global__ void gemm_mfma(const ushort* __restrict__ A, const ushort* __restrict__ Wt,
                          const float* __restrict__ bias, ushort* __restrict__ Cout,
                          int M, int KP, int Nc, int strideC, int ntiles,
                          float* __restrict__ csum, float* __restrict__ csq) {
    __shared__ ushort smem[64 * CT_STRIDE];  // 17408 B: union {As 8KB + Bs 8KB} / C-half-tile
    __shared__ float s_sum[128], s_sq[128];
    ushort* As = smem;
    ushort* Bs = smem + 4096;

    int tid = threadIdx.x;
    int w = tid >> 6, lane = tid & 63;
    int quad = lane >> 4, lr = lane & 15;
    int wm = w >> 1, wn = w & 1;
    int wg = xcd_swizzle(blockIdx.x, gridDim.x);
    int m0 = (wg / ntiles) * 128;
    int n0 = (wg % ntiles) * 128;

    if (tid < 128) { s_sum[tid] = 0.f; s_sq[tid] = 0.f; }

    // glds source chunk pre-swizzle: slot s of LDS row R holds global chunk s ^ ((R>>1)&3).
    const int kchunk = ((lane & 3) ^ ((lane >> 3) & 3)) * 8;
    const int grow = lane >> 2;
    const ushort* Abase = A + (size_t)m0 * KP + kchunk;
    const ushort* Bbase = Wt + (size_t)n0 * KP + kchunk;
    const int xq = (quad ^ ((lr >> 1) & 3)) * 8;  // matching swizzled read slot (halfwords)

    f32x4 acc[4][4] = {};

    for (int k0 = 0; k0 < KP; k0 += 32) {
#pragma unroll
        for (int c = w; c < 8; c += 4)
            __builtin_amdgcn_global_load_lds((const AS1 void*)(Abase + (size_t)(16 * c + grow) * KP + k0),
                                             (AS3 void*)(As + c * 512), 16, 0, 0);
#pragma unroll
        for (int c = w; c < 8; c += 4)
            __builtin_amdgcn_global_load_lds((const AS1 void*)(Bbase + (size_t)(16 * c + grow) * KP + k0),
                                             (AS3 void*)(Bs + c * 512), 16, 0, 0);
        __syncthreads();  // compiler emits vmcnt(0) drain here: exactly the needed semantics

        half8 a[4], b[4];
#pragma unroll
        for (int mf = 0; mf < 4; mf++)
            a[mf] = __builtin_bit_cast(half8, *(const short8*)(As + (64 * wm + 16 * mf + lr) * 32 + xq));
#pragma unroll
        for (int nf = 0; nf < 4; nf++)
            b[nf] = __builtin_bit_cast(half8, *(const short8*)(Bs + (64 * wn + 16 * nf + lr) * 32 + xq));
        __builtin_amdgcn_s_setprio(1);
#pragma unroll
        for (int mf = 0; mf < 4; mf++)
#pragma unroll
            for (int nf = 0; nf < 4; nf++)
                acc[mf][nf] = __builtin_amdgcn_mfma_f32_16x16x32_f16(a[mf], b[nf], acc[mf][nf], 0, 0, 0);
        __builtin_amdgcn_s_setprio(0);
        __syncthreads();  // staging buffer free for next K-step
    }

    // Epilogue: stats from regs + two 64-row half-tiles through LDS
#pragma unroll
    for (int half = 0; half < 2; half++) {
        if (wm == half) {
#pragma unroll
            for (int nf = 0; nf < 4; nf++) {
                int lcol = 64 * wn + 16 * nf + lr;
                int gn = n0 + lcol;
                float bv = (gn < Nc) ? bias[gn] : 0.f;
                float ps = 0.f, pq = 0.f;
#pragma unroll
                for (int mf = 0; mf < 4; mf++) {
#pragma unroll
                    for (int r = 0; r < 4; r++) {
                        int lrow = 16 * mf + quad * 4 + r;  // 0..63 within half
                        float v = acc[mf][nf][r] + bv;
                        smem[lrow * CT_STRIDE + lcol] = f2h(v);
                        if (m0 + 64 * half + lrow < M && gn < Nc) { ps += v; pq += v * v; }
                    }
                }
                if (gn < Nc) {
                    atomicAdd(&s_sum[lcol], ps);
                    atomicAdd(&s_sq[lcol], pq);
                }
            }
        }
        __syncthreads();
        // coalesced readback: 64 rows x 16 chunks of 8 fp16 (16B)
#pragma unroll
        for (int it = 0; it < 4; it++) {
            int idx = tid + it * 256;
            int row = idx >> 4, ch = idx & 15;
            int gcol = n0 + ch * 8;
            if (gcol < Nc) {  // Nc=600 is 8-aligned: chunks fully in/out
                *(short8*)(Cout + (size_t)(m0 + 64 * half + row) * strideC + gcol) =
                    *(const short8*)(smem + row * CT_STRIDE + ch * 8);
            }
        }
        __syncthreads();
    }

    if (tid < 128) {
        int gn = n0 + tid;
        if (gn < Nc) {
            atomicAdd(&csum[gn], s_sum[tid]);
            atomicAdd(&csq[gn], s_sq[tid]);
        }
    }
}

// ------- GEMM2 with fused BN1 bias+ReLU A-staging: h = max(yh + t1h, 0) @ Wt2^T + b2 --
// Same occupancy-first structure; A staged via regs (BN1+ReLU transform) each K-step.
__launch_bounds__(256, 6)
__global__ void gemm2_fused(const ushort* __restrict__ yh, const ushort* __restrict__ Wt,
                            const ushort* __restrict__ t1h, const float* __restrict__ bias,
                            ushort* __restrict__ hout,
                            float* __restrict__ csum, float* __restrict__ csq) {
    __shared__ ushort smem[64 * CT_STRIDE];  // union {As 8KB + Bs 8KB} / C-half-tile
    __shared__ ushort s_t[KP2];
    __shared__ float s_sum[128], s_sq[128];
    ushort* As = smem;
    ushort* Bs = smem + 4096;

    int tid = threadIdx.x;
    int w = tid >> 6, lane = tid & 63;
    int quad = lane >> 4, lr = lane & 15;
    int wm = w >> 1, wn = w & 1;
    int wg = xcd_swizzle(blockIdx.x, gridDim.x);
    int m0 = (wg / 3) * 128;
    int n0 = (wg % 3) * 128;

    int r0 = tid >> 2;          // 0..63; thread also handles r0+64
    int q = tid & 3;            // col-chunk index within 32
    int cc = q * 8;
    const int aslot = (q ^ ((r0 >> 1) & 3)) * 8;  // swizzled ds_write slot (halfwords)

    const int kchunk = ((lane & 3) ^ ((lane >> 3) & 3)) * 8;
    const int grow = lane >> 2;
    const ushort* Bbase = Wt + (size_t)n0 * KP2 + kchunk;
    const int xq = (quad ^ ((lr >> 1) & 3)) * 8;

    const ushort* yrow0 = yh + (size_t)(m0 + r0) * DIM2 + cc;
    const ushort* yrow1 = yh + (size_t)(m0 + r0 + 64) * DIM2 + cc;

    if (tid < 128) { s_sum[tid] = 0.f; s_sq[tid] = 0.f; }
    for (int i = tid; i < KP2 / 2; i += 256) ((uint*)s_t)[i] = ((const uint*)t1h)[i];
    __syncthreads();

    f32x4 acc[4][4] = {};
    const int nk = KP2 >> 5;  // 19

    for (int t = 0; t < nk; ++t) {
        int k0 = t << 5;
#pragma unroll
        for (int c = w; c < 8; c += 4)
            __builtin_amdgcn_global_load_lds((const AS1 void*)(Bbase + (size_t)(16 * c + grow) * KP2 + k0),
                                             (AS3 void*)(Bs + c * 512), 16, 0, 0);
        int col = k0 + cc;
        half8 a0 = {}, a1 = {};
        if (col < DIM2) {
            half8 tt = *(const half8*)(s_t + col);
            half8 y0 = *(const half8*)(yrow0 + k0);
            half8 y1 = *(const half8*)(yrow1 + k0);
            half8 z = {};
            a0 = __builtin_elementwise_max(y0 + tt, z);
            a1 = __builtin_elementwise_max(y1 + tt, z);
        }
        *(short8*)(As + r0 * 32 + aslot) = __builtin_bit_cast(short8, a0);
        *(short8*)(As + (r0 + 64) * 32 + aslot) = __builtin_bit_cast(short8, a1);
        __syncthreads();

        half8 a[4], b[4];
#pragma unroll
        for (int mf = 0; mf < 4; mf++)
            a[mf] = __builtin_bit_cast(half8, *(const short8*)(As + (64 * wm + 16 * mf + lr) * 32 + xq));
#pragma unroll
        for (int nf = 0; nf < 4; nf++)
            b[nf] = __builtin_bit_cast(half8, *(const short8*)(Bs + (64 * wn + 16 * nf + lr) * 32 + xq));
        __builtin_amdgcn_s_setprio(1);
#pragma unroll
        for (int mf = 0; mf < 4; mf++)
#pragma unroll
            for (int nf = 0; nf < 4; nf++)
                acc[mf][nf] = __builtin_amdgcn_mfma_f32_16x16x32_f16(a[mf], b[nf], acc[mf][nf], 0, 0, 0);
        __builtin_amdgcn_s_setprio(0);
        __syncthreads();
    }

    // Epilogue: stats from regs + two 64-row half-tiles through LDS
#pragma unroll
    for (int half = 0; half < 2; half++) {
        if (wm == half) {
#pragma unroll
            for (int nf = 0; nf < 4; nf++) {
                int lcol = 64 * wn + 16 * nf + lr;
                int gn = n0 + lcol;
                float bv = (gn < DIM) ? bias[gn] : 0.f;
                float ps = 0.f, pq = 0.f;
#pragma unroll
                for (int mf = 0; mf < 4; mf++) {
#pragma unroll
                    for (int r = 0; r < 4; r++) {
                        int lrow = 16 * mf + quad * 4 + r;  // 0..63 within half
                        float v = acc[mf][nf][r] + bv;
                        smem[lrow * CT_STRIDE + lcol] = f2h(v);
                        if (m0 + 64 * half + lrow < N_NODES && gn < DIM) { ps += v; pq += v * v; }
                    }
                }
                if (gn < DIM) {
                    atomicAdd(&s_sum[lcol], ps);
                    atomicAdd(&s_sq[lcol], pq);
                }
            }
        }
        __syncthreads();
        // coalesced readback: 64 rows x 32 chunks of 4 fp16 (8B); DIM=300 is 4-aligned
#pragma unroll
        for (int it = 0; it < 8; it++) {
            int idx = tid + it * 256;
            int row = idx >> 5, ch = idx & 31;
            int gm = m0 + 64 * half + row, gcol = n0 + ch * 4;
            if (gm < N_NODES && gcol < DIM) {
                *(uint2*)(hout + (size_t)gm * DIM + gcol) =
                    *(const uint2*)(smem + row * CT_STRIDE + ch * 4);
            }
        }
        __syncthreads();
    }

    if (tid < 128) {
        int gn = n0 + tid;
        if (gn < DIM) {
            atomicAdd(&csum[gn], s_sum[tid]);
            atomicAdd(&csq[gn], s_sq[tid]);
        }
    }
}

// ---------------- BN stats -> per-column scale/shift (+optional fp16 t' = shift/scale) -
__global__ void bn_finalize(const float* __restrict__ sum, const float* __restrict__ sq,
                            const float* __restrict__ g, const float* __restrict__ b,
                            float* __restrict__ scale, float* __restrict__ shift,
                            ushort* __restrict__ th, int n, int npad) {
    int i = blockIdx.x * blockDim.x + threadIdx.x;
    if (i >= n) {
        if (th && i < npad) th[i] = 0;
        return;
    }
    const float invN = 1.0f / (float)N_NODES;
    float m = sum[i] * invN;
    float v = sq[i] * invN - m * m;
    float inv = rsqrtf(v + 1e-5f);
    float sc = g[i] * inv;
    scale[i] = sc;
    shift[i] = b[i] - m * sc;
    if (th) th[i] = f2h((b[i] - m * sc) / sc);  // scale > 0 (g1 = ones)
}

// ---------------- Final output: BN2 of last layer from fp16 h -> fp32 out -------------
__global__ void bn_apply_out(const ushort* __restrict__ h, const float* __restrict__ scale,
                             const float* __restrict__ shift, float* __restrict__ out) {
    int idx = blockIdx.x * blockDim.x + threadIdx.x;  // pair index
    const int PAIRS = DIM / 2;
    if (idx >= N_NODES * PAIRS) return;
    int p = idx % PAIRS;
    uint u = ((const uint*)h)[idx];
    float2 sc = *(const float2*)(scale + 2 * p);
    float2 sh = *(const float2*)(shift + 2 * p);
    float2 o;
    o.x = h2f((ushort)(u & 0xffffu)) * sc.x + sh.x;
    o.y = h2f((ushort)(u >> 16)) * sc.y + sh.y;
    *(float2*)(out + 2 * idx) = o;
}

extern "C" void kernel_launch(void* const* d_in, const int* in_sizes, int n_in,
                              void* d_out, int out_size, void* d_ws, size_t ws_size,
                              hipStream_t stream) {
    const int* x = (const int*)d_in[0];
    const int* ei = (const int*)d_in[1];
    const int* ea = (const int*)d_in[2];
    const float* atom_emb = (const float*)d_in[3];
    const float* bond_emb = (const float*)d_in[4];
    const float* eps = (const float*)d_in[5];
    const float* W1 = (const float*)d_in[6];
    const float* b1 = (const float*)d_in[7];
    const float* g1 = (const float*)d_in[8];
    const float* be1 = (const float*)d_in[9];
    const float* W2 = (const float*)d_in[10];
    const float* b2 = (const float*)d_in[11];
    const float* gamma = (const float*)d_in[12];
    const float* beta = (const float*)d_in[13];
    float* out = (float*)d_out;

    float* ws = (float*)d_ws;
    ushort* h    = (ushort*)ws;                          // N*DIM us = 7,500,000 f
    ushort* A1h  = (ushort*)(ws + 7500000);              // MPAD*KP1 us = 8,007,680 f
    ushort* yh   = (ushort*)(ws + 15507680);             // MPAD*DIM2 us = 15,014,400 f
    ushort* Wt1  = (ushort*)(ws + 30522080);             // NP1*KP1 us = 102,400 f
    ushort* Wt2  = (ushort*)(ws + 30624480);             // NP2*KP2 us = 116,736 f
    ushort* bondh = (ushort*)(ws + 30741216);            // 48*DIM us = 7,200 f
    float* stats = ws + 30748416;                        // 3,600 f
    ushort* t1h  = (ushort*)(ws + 30752016);             // KP2 us = 304 f
    int* rowstart = (int*)(ws + 30752320);               // N+1
    int* deg      = rowstart + 50001;
    int* cursor   = deg + 50000;
    int2* epack   = (int2*)(cursor + 50000 + 1);         // align to 8B
    int* bsum     = (int*)(epack + 250000);              // SCAN_BLOCKS

    float* sum1 = stats;
    float* sq1  = stats + 600;
    float* sum2 = stats + 1200;
    float* sq2  = stats + 1500;
    float* scale1 = stats + 1800;
    float* shift1 = stats + 2400;
    float* scale2 = stats + 3000;
    float* shift2 = stats + 3300;

    const int PAIRS_N = N_NODES * (DIM / 2);

    // CSR build (once; edge_index is layer-invariant)
    hipMemsetAsync(deg, 0, 50000 * sizeof(int), stream);
    deg_count<<<(N_EDGES + 255) / 256, 256, 0, stream>>>(ei, deg);
    block_sums<<<SCAN_BLOCKS, 256, 0, stream>>>(deg, bsum);
    scan_bsums<<<1, 256, 0, stream>>>(bsum);
    write_rowstart<<<SCAN_BLOCKS, 256, 0, stream>>>(deg, bsum, rowstart, cursor);
    csr_fill<<<(N_EDGES + 255) / 256, 256, 0, stream>>>(ei, ea, cursor, epack);

    atom_enc<<<(PAIRS_N + 255) / 256, 256, 0, stream>>>(x, atom_emb, h);
    init_bn<<<(DIM + 255) / 256, 256, 0, stream>>>(scale2, shift2);

    for (int l = 0; l < NL; ++l) {
        hipMemsetAsync(stats, 0, 1800 * sizeof(float), stream);

        bond_conv<<<(48 * (DIM / 2) + 255) / 256, 256, 0, stream>>>(
            bond_emb + (size_t)l * 3 * 16 * DIM, bondh);

        agg_combine<<<(MPAD + 3) / 4, 256, 0, stream>>>(rowstart, epack, bondh,
                                                        h, scale2, shift2, (l > 0) ? 1 : 0,
                                                        eps, l, A1h);

        wt_conv<<<(KP1 * NP1 + 255) / 256, 256, 0, stream>>>(W1 + (size_t)l * DIM * DIM2, Wt1,
                                                             DIM, DIM2, KP1, NP1);

        gemm_mfma<<<(MPAD / 128) * (NP1 / 128), 256, 0, stream>>>(
            A1h, Wt1, b1 + l * DIM2, yh, N_NODES, KP1, DIM2, DIM2, NP1 / 128, sum1, sq1);

        bn_finalize<<<(KP2 + 255) / 256, 256, 0, stream>>>(sum1, sq1, g1 + l * DIM2,
                                                           be1 + l * DIM2, scale1, shift1,
                                                           t1h, DIM2, KP2);

        wt_conv2<<<(KP2 * NP2 + 255) / 256, 256, 0, stream>>>(W2 + (size_t)l * DIM2 * DIM,
                                                              scale1, Wt2);

        gemm2_fused<<<(MPAD / 128) * (NP2 / 128), 256, 0, stream>>>(
            yh, Wt2, t1h, b2 + l * DIM, h, sum2, sq2);

        bn_finalize<<<(DIM + 255) / 256, 256, 0, stream>>>(sum2, sq2, gamma + l * DIM,
                                                           beta + l * DIM, scale2, shift2,
                                                           nullptr, DIM, DIM);
    }

    // final output: BN2 of last layer, no ReLU
    bn_apply_out<<<(PAIRS_N + 255) / 256, 256, 0, stream>>>(h, scale2, shift2, out);
}

// Round 3
// 1159.992 us; speedup vs baseline: 2.7096x; 2.7096x over previous
//
#include <hip/hip_runtime.h>

#define N_NODES 50000
#define N_EDGES 250000
#define DIM 300
#define DIM2 600
#define NL 5
#define MPAD 50048      // 391 * 128
#define KP1 320         // DIM padded to mult of 32
#define KP2 608         // DIM2 padded to mult of 32
#define NP1 640         // DIM2 padded to mult of 128
#define NP2 384         // DIM padded to mult of 128
#define SCAN_BLOCKS 196 // ceil(N_NODES / 256)
#define CT_STRIDE 136   // 128 + 8 pad: breaks epilogue LDS write conflicts

typedef __attribute__((ext_vector_type(8))) _Float16 half8;
typedef __attribute__((ext_vector_type(2))) _Float16 half2v;
typedef __attribute__((ext_vector_type(8))) short short8;
typedef __attribute__((ext_vector_type(4))) float f32x4;
typedef unsigned short ushort;
typedef unsigned int uint;

#define AS1 __attribute__((address_space(1)))
#define AS3 __attribute__((address_space(3)))

static __device__ __forceinline__ ushort f2h(float f) {
    _Float16 h = (_Float16)f;
    return __builtin_bit_cast(ushort, h);
}
static __device__ __forceinline__ float h2f(ushort s) {
    return (float)__builtin_bit_cast(_Float16, s);
}
static __device__ __forceinline__ uint pk2(float a, float b) {
    return (uint)f2h(a) | ((uint)f2h(b) << 16);
}
static __device__ __forceinline__ half2v u2h2(uint u) {
    return __builtin_bit_cast(half2v, u);
}

// bijective XCD-contiguous remap (m204): hardware assigns block o -> XCD o%8;
// give each XCD a contiguous run of logical tiles so an m-band's n-tiles share L2.
static __device__ __forceinline__ int xcd_swizzle(int o, int nwg) {
    int q = nwg >> 3, r = nwg & 7;
    int xcd = o & 7, idx = o >> 3;
    return (xcd < r ? xcd * (q + 1) : r * (q + 1) + (xcd - r) * q) + idx;
}

// ---------------- Atom encoder -> h fp16 ----------------
__global__ void atom_enc(const int* __restrict__ x, const float* __restrict__ emb,
                         ushort* __restrict__ h) {
    int idx = blockIdx.x * blockDim.x + threadIdx.x;  // pair index
    const int PAIRS = DIM / 2;  // 150
    if (idx >= N_NODES * PAIRS) return;
    int n = idx / PAIRS, p = idx - n * PAIRS;
    const int* xr = x + n * 9;
    float s0 = 0.f, s1 = 0.f;
#pragma unroll
    for (int i = 0; i < 9; i++) {
        const float2 v = *(const float2*)(emb + (size_t)(i * 128 + xr[i]) * DIM + 2 * p);
        s0 += v.x; s1 += v.y;
    }
    ((uint*)h)[idx] = pk2(s0, s1);
}

// ---------------- CSR build (once per launch; edge_index is layer-invariant) ----------
__global__ void deg_count(const int* __restrict__ ei, int* __restrict__ deg) {
    int e = blockIdx.x * blockDim.x + threadIdx.x;
    if (e < N_EDGES) atomicAdd(&deg[ei[N_EDGES + e]], 1);
}

__global__ void block_sums(const int* __restrict__ deg, int* __restrict__ bsum) {
    __shared__ int red[256];
    int tid = threadIdx.x;
    int node = blockIdx.x * 256 + tid;
    red[tid] = (node < N_NODES) ? deg[node] : 0;
    __syncthreads();
    for (int off = 128; off > 0; off >>= 1) {
        if (tid < off) red[tid] += red[tid + off];
        __syncthreads();
    }
    if (tid == 0) bsum[blockIdx.x] = red[0];
}

__global__ void scan_bsums(int* __restrict__ bsum) {
    __shared__ int s[256];
    int tid = threadIdx.x;
    int orig = (tid < SCAN_BLOCKS) ? bsum[tid] : 0;
    s[tid] = orig;
    __syncthreads();
    for (int off = 1; off < 256; off <<= 1) {
        int v = (tid >= off) ? s[tid - off] : 0;
        __syncthreads();
        s[tid] += v;
        __syncthreads();
    }
    if (tid < SCAN_BLOCKS) bsum[tid] = s[tid] - orig;  // exclusive
}

__global__ void write_rowstart(const int* __restrict__ deg, const int* __restrict__ bsum,
                               int* __restrict__ rowstart, int* __restrict__ cursor) {
    __shared__ int s[256];
    int tid = threadIdx.x;
    int node = blockIdx.x * 256 + tid;
    int d = (node < N_NODES) ? deg[node] : 0;
    s[tid] = d;
    __syncthreads();
    for (int off = 1; off < 256; off <<= 1) {
        int v = (tid >= off) ? s[tid - off] : 0;
        __syncthreads();
        s[tid] += v;
        __syncthreads();
    }
    int excl = s[tid] - d + bsum[blockIdx.x];
    if (node < N_NODES) {
        rowstart[node] = excl;
        cursor[node] = excl;
    }
    if (blockIdx.x == 0 && tid == 0) rowstart[N_NODES] = N_EDGES;
}

// fill CSR with pre-packed edge payload: (src, a0|a1<<8|a2<<16)
__global__ void csr_fill(const int* __restrict__ ei, const int* __restrict__ ea,
                         int* __restrict__ cursor, int2* __restrict__ epack) {
    int e = blockIdx.x * blockDim.x + threadIdx.x;
    if (e < N_EDGES) {
        int d = ei[N_EDGES + e];
        int slot = atomicAdd(&cursor[d], 1);
        int attr = ea[3 * e] | (ea[3 * e + 1] << 8) | (ea[3 * e + 2] << 16);
        epack[slot] = make_int2(ei[e], attr);
    }
}

// ---------------- per-layer bond table fp32 -> fp16 (28.8 KB, L1-resident) ----------
__global__ void bond_conv(const float* __restrict__ bond, ushort* __restrict__ bondh) {
    int idx = blockIdx.x * blockDim.x + threadIdx.x;  // pair index
    if (idx >= 48 * (DIM / 2)) return;
    float2 v = *(const float2*)(bond + 2 * idx);
    ((uint*)bondh)[idx] = pk2(v.x, v.y);
}

// ---------------- identity BN params for layer 0 ----------------
__global__ void init_bn(float* __restrict__ scale, float* __restrict__ shift) {
    int i = blockIdx.x * blockDim.x + threadIdx.x;
    if (i < DIM) { scale[i] = 1.f; shift[i] = 0.f; }
}

// ------- Fused BN2(+ReLU) on-load + gather-aggregate + GIN combine + fp16 cast --------
__launch_bounds__(256)
__global__ void agg_combine(const int* __restrict__ rowstart, const int2* __restrict__ epack,
                            const ushort* __restrict__ bondh, const ushort* __restrict__ h,
                            const float* __restrict__ scale, const float* __restrict__ shift,
                            int relu, const float* __restrict__ epsp, int layer,
                            ushort* __restrict__ A1) {
    int node = blockIdx.x * 4 + (threadIdx.x >> 6);
    int lane = threadIdx.x & 63;
    if (node >= MPAD) return;
    uint* row32 = (uint*)(A1 + (size_t)node * KP1);
    if (node >= N_NODES) {
        for (int i = lane; i < KP1 / 2; i += 64) row32[i] = 0;
        return;
    }
    const int PAIRS = DIM / 2;  // 150
    float2 scf[3], shf[3];
    half2v sch[3], shh[3];
#pragma unroll
    for (int i = 0; i < 3; i++) {
        int p = lane + 64 * i;
        scf[i] = make_float2(0.f, 0.f);
        shf[i] = make_float2(0.f, 0.f);
        if (p < PAIRS) {
            scf[i] = *(const float2*)(scale + 2 * p);
            shf[i] = *(const float2*)(shift + 2 * p);
        }
        sch[i] = half2v{(_Float16)scf[i].x, (_Float16)scf[i].y};
        shh[i] = half2v{(_Float16)shf[i].x, (_Float16)shf[i].y};
    }
    float epsv = 1.0f + epsp[layer];
    const uint* hd = (const uint*)(h + (size_t)node * DIM);
    float ax[3], ay[3];
#pragma unroll
    for (int i = 0; i < 3; i++) {
        int p = lane + 64 * i;
        ax[i] = 0.f; ay[i] = 0.f;
        if (p < PAIRS) {
            uint u = hd[p];
            float vx = h2f((ushort)(u & 0xffffu)) * scf[i].x + shf[i].x;
            float vy = h2f((ushort)(u >> 16)) * scf[i].y + shf[i].y;
            if (relu) { vx = fmaxf(vx, 0.f); vy = fmaxf(vy, 0.f); }
            ax[i] = epsv * vx; ay[i] = epsv * vy;
        }
    }

    auto edge_contrib = [&](int2 pk) {
        const uint* hs = (const uint*)(h + (size_t)pk.x * DIM);
        int a0 = pk.y & 0xff, a1v = (pk.y >> 8) & 0xff, a2 = (pk.y >> 16) & 0xff;
        const uint* t0 = (const uint*)(bondh + a0 * DIM);
        const uint* t1 = (const uint*)(bondh + (16 + a1v) * DIM);
        const uint* t2 = (const uint*)(bondh + (32 + a2) * DIM);
        const half2v z = {};
#pragma unroll
        for (int i = 0; i < 3; i++) {
            int p = lane + 64 * i;
            if (p < PAIRS) {
                half2v hv = u2h2(hs[p]) * sch[i] + shh[i];
                if (relu) hv = __builtin_elementwise_max(hv, z);
                half2v m = hv + u2h2(t0[p]) + u2h2(t1[p]) + u2h2(t2[p]);
                m = __builtin_elementwise_max(m, z);
                ax[i] += (float)m.x;
                ay[i] += (float)m.y;
            }
        }
    };

    int e0 = rowstart[node], e1 = rowstart[node + 1];
    int t = e0;
    for (; t + 1 < e1; t += 2) {
        int2 p0 = epack[t];
        int2 p1 = epack[t + 1];
        edge_contrib(p0);
        edge_contrib(p1);
    }
    if (t < e1) edge_contrib(epack[t]);

#pragma unroll
    for (int i = 0; i < 3; i++) {
        int p = lane + 64 * i;
        if (p < KP1 / 2) row32[p] = (p < PAIRS) ? pk2(ax[i], ay[i]) : 0u;
    }
}

// ---------------- W1 (K x N) -> Wt fp16 [NP x KP] transposed, zero-padded ----------
__global__ void wt_conv(const float* __restrict__ W, ushort* __restrict__ Wt,
                        int K, int Nc, int KP, int NP) {
    int idx = blockIdx.x * blockDim.x + threadIdx.x;
    if (idx >= KP * NP) return;
    int k = idx / NP, n = idx - k * NP;
    ushort v = 0;
    if (k < K && n < Nc) v = f2h(W[(size_t)k * Nc + n]);
    Wt[(size_t)n * KP + k] = v;
}

// ------- W2 with BN1 scale folded: Wt2[n][k] = fp16(scale1[k] * W2[k][n]) -------------
__global__ void wt_conv2(const float* __restrict__ W, const float* __restrict__ scale,
                         ushort* __restrict__ Wt) {
    int idx = blockIdx.x * blockDim.x + threadIdx.x;
    if (idx >= KP2 * NP2) return;
    int k = idx / NP2, n = idx - k * NP2;
    ushort v = 0;
    if (k < DIM2 && n < DIM) v = f2h(scale[k] * W[(size_t)k * DIM + n]);
    Wt[(size_t)n * KP2 + k] = v;
}

// ---------------- GEMM1: yh = A1 @ Wt1^T + b1, fp16 out + BN stats --------------------
// Occupancy-first structure: single-buffered 2-phase K-loop (inter-block TLP hides
// the staging drain), chunk-XOR LDS swizzle (conflict-free ds_read_b128),
// 64-row half-tile C epilogue. LDS 18.4 KB; natural VGPR (~76) -> ~6 blocks/CU.
__launch_bounds__(256)
__global__ void gemm_mfma(const ushort* __restrict__ A, const ushort* __restrict__ Wt,
                          const float* __restrict__ bias, ushort* __restrict__ Cout,
                          int M, int KP, int Nc, int strideC, int ntiles,
                          float* __restrict__ csum, float* __restrict__ csq) {
    __shared__ ushort smem[64 * CT_STRIDE];  // 17408 B: union {As 8KB + Bs 8KB} / C-half-tile
    __shared__ float s_sum[128], s_sq[128];
    ushort* As = smem;
    ushort* Bs = smem + 4096;

    int tid = threadIdx.x;
    int w = tid >> 6, lane = tid & 63;
    int quad = lane >> 4, lr = lane & 15;
    int wm = w >> 1, wn = w & 1;
    int wg = xcd_swizzle(blockIdx.x, gridDim.x);
    int m0 = (wg / ntiles) * 128;
    int n0 = (wg % ntiles) * 128;

    if (tid < 128) { s_sum[tid] = 0.f; s_sq[tid] = 0.f; }

    // glds source chunk pre-swizzle: slot s of LDS row R holds global chunk s ^ ((R>>1)&3).
    const int kchunk = ((lane & 3) ^ ((lane >> 3) & 3)) * 8;
    const int grow = lane >> 2;
    const ushort* Abase = A + (size_t)m0 * KP + kchunk;
    const ushort* Bbase = Wt + (size_t)n0 * KP + kchunk;
    const int xq = (quad ^ ((lr >> 1) & 3)) * 8;  // matching swizzled read slot (halfwords)

    f32x4 acc[4][4] = {};

    for (int k0 = 0; k0 < KP; k0 += 32) {
#pragma unroll
        for (int c = w; c < 8; c += 4)
            __builtin_amdgcn_global_load_lds((const AS1 void*)(Abase + (size_t)(16 * c + grow) * KP + k0),
                                             (AS3 void*)(As + c * 512), 16, 0, 0);
#pragma unroll
        for (int c = w; c < 8; c += 4)
            __builtin_amdgcn_global_load_lds((const AS1 void*)(Bbase + (size_t)(16 * c + grow) * KP + k0),
                                             (AS3 void*)(Bs + c * 512), 16, 0, 0);
        __syncthreads();  // compiler emits vmcnt(0) drain here: exactly the needed semantics

        half8 a[4], b[4];
#pragma unroll
        for (int mf = 0; mf < 4; mf++)
            a[mf] = __builtin_bit_cast(half8, *(const short8*)(As + (64 * wm + 16 * mf + lr) * 32 + xq));
#pragma unroll
        for (int nf = 0; nf < 4; nf++)
            b[nf] = __builtin_bit_cast(half8, *(const short8*)(Bs + (64 * wn + 16 * nf + lr) * 32 + xq));
        __builtin_amdgcn_s_setprio(1);
#pragma unroll
        for (int mf = 0; mf < 4; mf++)
#pragma unroll
            for (int nf = 0; nf < 4; nf++)
                acc[mf][nf] = __builtin_amdgcn_mfma_f32_16x16x32_f16(a[mf], b[nf], acc[mf][nf], 0, 0, 0);
        __builtin_amdgcn_s_setprio(0);
        __syncthreads();  // staging buffer free for next K-step
    }

    // Epilogue: stats from regs + two 64-row half-tiles through LDS
#pragma unroll
    for (int half = 0; half < 2; half++) {
        if (wm == half) {
#pragma unroll
            for (int nf = 0; nf < 4; nf++) {
                int lcol = 64 * wn + 16 * nf + lr;
                int gn = n0 + lcol;
                float bv = (gn < Nc) ? bias[gn] : 0.f;
                float ps = 0.f, pq = 0.f;
#pragma unroll
                for (int mf = 0; mf < 4; mf++) {
#pragma unroll
                    for (int r = 0; r < 4; r++) {
                        int lrow = 16 * mf + quad * 4 + r;  // 0..63 within half
                        float v = acc[mf][nf][r] + bv;
                        smem[lrow * CT_STRIDE + lcol] = f2h(v);
                        if (m0 + 64 * half + lrow < M && gn < Nc) { ps += v; pq += v * v; }
                    }
                }
                if (gn < Nc) {
                    atomicAdd(&s_sum[lcol], ps);
                    atomicAdd(&s_sq[lcol], pq);
                }
            }
        }
        __syncthreads();
        // coalesced readback: 64 rows x 16 chunks of 8 fp16 (16B)
#pragma unroll
        for (int it = 0; it < 4; it++) {
            int idx = tid + it * 256;
            int row = idx >> 4, ch = idx & 15;
            int gcol = n0 + ch * 8;
            if (gcol < Nc) {  // Nc=600 is 8-aligned: chunks fully in/out
                *(short8*)(Cout + (size_t)(m0 + 64 * half + row) * strideC + gcol) =
                    *(const short8*)(smem + row * CT_STRIDE + ch * 8);
            }
        }
        __syncthreads();
    }

    if (tid < 128) {
        int gn = n0 + tid;
        if (gn < Nc) {
            atomicAdd(&csum[gn], s_sum[tid]);
            atomicAdd(&csq[gn], s_sq[tid]);
        }
    }
}

// ------- GEMM2 with fused BN1 bias+ReLU A-staging: h = max(yh + t1h, 0) @ Wt2^T + b2 --
// Same occupancy-first structure; A staged via regs (BN1+ReLU transform) each K-step.
__launch_bounds__(256)
__global__ void gemm2_fused(const ushort* __restrict__ yh, const ushort* __restrict__ Wt,
                            const ushort* __restrict__ t1h, const float* __restrict__ bias,
                            ushort* __restrict__ hout,
                            float* __restrict__ csum, float* __restrict__ csq) {
    __shared__ ushort smem[64 * CT_STRIDE];  // union {As 8KB + Bs 8KB} / C-half-tile
    __shared__ ushort s_t[KP2];
    __shared__ float s_sum[128], s_sq[128];
    ushort* As = smem;
    ushort* Bs = smem + 4096;

    int tid = threadIdx.x;
    int w = tid >> 6, lane = tid & 63;
    int quad = lane >> 4, lr = lane & 15;
    int wm = w >> 1, wn = w & 1;
    int wg = xcd_swizzle(blockIdx.x, gridDim.x);
    int m0 = (wg / 3) * 128;
    int n0 = (wg % 3) * 128;

    int r0 = tid >> 2;          // 0..63; thread also handles r0+64
    int q = tid & 3;            // col-chunk index within 32
    int cc = q * 8;
    const int aslot = (q ^ ((r0 >> 1) & 3)) * 8;  // swizzled ds_write slot (halfwords)

    const int kchunk = ((lane & 3) ^ ((lane >> 3) & 3)) * 8;
    const int grow = lane >> 2;
    const ushort* Bbase = Wt + (size_t)n0 * KP2 + kchunk;
    const int xq = (quad ^ ((lr >> 1) & 3)) * 8;

    const ushort* yrow0 = yh + (size_t)(m0 + r0) * DIM2 + cc;
    const ushort* yrow1 = yh + (size_t)(m0 + r0 + 64) * DIM2 + cc;

    if (tid < 128) { s_sum[tid] = 0.f; s_sq[tid] = 0.f; }
    for (int i = tid; i < KP2 / 2; i += 256) ((uint*)s_t)[i] = ((const uint*)t1h)[i];
    __syncthreads();

    f32x4 acc[4][4] = {};
    const int nk = KP2 >> 5;  // 19

    for (int t = 0; t < nk; ++t) {
        int k0 = t << 5;
#pragma unroll
        for (int c = w; c < 8; c += 4)
            __builtin_amdgcn_global_load_lds((const AS1 void*)(Bbase + (size_t)(16 * c + grow) * KP2 + k0),
                                             (AS3 void*)(Bs + c * 512), 16, 0, 0);
        int col = k0 + cc;
        half8 a0 = {}, a1 = {};
        if (col < DIM2) {
            half8 tt = *(const half8*)(s_t + col);
            half8 y0 = *(const half8*)(yrow0 + k0);
            half8 y1 = *(const half8*)(yrow1 + k0);
            half8 z = {};
            a0 = __builtin_elementwise_max(y0 + tt, z);
            a1 = __builtin_elementwise_max(y1 + tt, z);
        }
        *(short8*)(As + r0 * 32 + aslot) = __builtin_bit_cast(short8, a0);
        *(short8*)(As + (r0 + 64) * 32 + aslot) = __builtin_bit_cast(short8, a1);
        __syncthreads();

        half8 a[4], b[4];
#pragma unroll
        for (int mf = 0; mf < 4; mf++)
            a[mf] = __builtin_bit_cast(half8, *(const short8*)(As + (64 * wm + 16 * mf + lr) * 32 + xq));
#pragma unroll
        for (int nf = 0; nf < 4; nf++)
            b[nf] = __builtin_bit_cast(half8, *(const short8*)(Bs + (64 * wn + 16 * nf + lr) * 32 + xq));
        __builtin_amdgcn_s_setprio(1);
#pragma unroll
        for (int mf = 0; mf < 4; mf++)
#pragma unroll
            for (int nf = 0; nf < 4; nf++)
                acc[mf][nf] = __builtin_amdgcn_mfma_f32_16x16x32_f16(a[mf], b[nf], acc[mf][nf], 0, 0, 0);
        __builtin_amdgcn_s_setprio(0);
        __syncthreads();
    }

    // Epilogue: stats from regs + two 64-row half-tiles through LDS
#pragma unroll
    for (int half = 0; half < 2; half++) {
        if (wm == half) {
#pragma unroll
            for (int nf = 0; nf < 4; nf++) {
                int lcol = 64 * wn + 16 * nf + lr;
                int gn = n0 + lcol;
                float bv = (gn < DIM) ? bias[gn] : 0.f;
                float ps = 0.f, pq = 0.f;
#pragma unroll
                for (int mf = 0; mf < 4; mf++) {
#pragma unroll
                    for (int r = 0; r < 4; r++) {
                        int lrow = 16 * mf + quad * 4 + r;  // 0..63 within half
                        float v = acc[mf][nf][r] + bv;
                        smem[lrow * CT_STRIDE + lcol] = f2h(v);
                        if (m0 + 64 * half + lrow < N_NODES && gn < DIM) { ps += v; pq += v * v; }
                    }
                }
                if (gn < DIM) {
                    atomicAdd(&s_sum[lcol], ps);
                    atomicAdd(&s_sq[lcol], pq);
                }
            }
        }
        __syncthreads();
        // coalesced readback: 64 rows x 32 chunks of 4 fp16 (8B); DIM=300 is 4-aligned
#pragma unroll
        for (int it = 0; it < 8; it++) {
            int idx = tid + it * 256;
            int row = idx >> 5, ch = idx & 31;
            int gm = m0 + 64 * half + row, gcol = n0 + ch * 4;
            if (gm < N_NODES && gcol < DIM) {
                *(uint2*)(hout + (size_t)gm * DIM + gcol) =
                    *(const uint2*)(smem + row * CT_STRIDE + ch * 4);
            }
        }
        __syncthreads();
    }

    if (tid < 128) {
        int gn = n0 + tid;
        if (gn < DIM) {
            atomicAdd(&csum[gn], s_sum[tid]);
            atomicAdd(&csq[gn], s_sq[tid]);
        }
    }
}

// ---------------- BN stats -> per-column scale/shift (+optional fp16 t' = shift/scale) -
__global__ void bn_finalize(const float* __restrict__ sum, const float* __restrict__ sq,
                            const float* __restrict__ g, const float* __restrict__ b,
                            float* __restrict__ scale, float* __restrict__ shift,
                            ushort* __restrict__ th, int n, int npad) {
    int i = blockIdx.x * blockDim.x + threadIdx.x;
    if (i >= n) {
        if (th && i < npad) th[i] = 0;
        return;
    }
    const float invN = 1.0f / (float)N_NODES;
    float m = sum[i] * invN;
    float v = sq[i] * invN - m * m;
    float inv = rsqrtf(v + 1e-5f);
    float sc = g[i] * inv;
    scale[i] = sc;
    shift[i] = b[i] - m * sc;
    if (th) th[i] = f2h((b[i] - m * sc) / sc);  // scale > 0 (g1 = ones)
}

// ---------------- Final output: BN2 of last layer from fp16 h -> fp32 out -------------
__global__ void bn_apply_out(const ushort* __restrict__ h, const float* __restrict__ scale,
                             const float* __restrict__ shift, float* __restrict__ out) {
    int idx = blockIdx.x * blockDim.x + threadIdx.x;  // pair index
    const int PAIRS = DIM / 2;
    if (idx >= N_NODES * PAIRS) return;
    int p = idx % PAIRS;
    uint u = ((const uint*)h)[idx];
    float2 sc = *(const float2*)(scale + 2 * p);
    float2 sh = *(const float2*)(shift + 2 * p);
    float2 o;
    o.x = h2f((ushort)(u & 0xffffu)) * sc.x + sh.x;
    o.y = h2f((ushort)(u >> 16)) * sc.y + sh.y;
    *(float2*)(out + 2 * idx) = o;
}

extern "C" void kernel_launch(void* const* d_in, const int* in_sizes, int n_in,
                              void* d_out, int out_size, void* d_ws, size_t ws_size,
                              hipStream_t stream) {
    const int* x = (const int*)d_in[0];
    const int* ei = (const int*)d_in[1];
    const int* ea = (const int*)d_in[2];
    const float* atom_emb = (const float*)d_in[3];
    const float* bond_emb = (const float*)d_in[4];
    const float* eps = (const float*)d_in[5];
    const float* W1 = (const float*)d_in[6];
    const float* b1 = (const float*)d_in[7];
    const float* g1 = (const float*)d_in[8];
    const float* be1 = (const float*)d_in[9];
    const float* W2 = (const float*)d_in[10];
    const float* b2 = (const float*)d_in[11];
    const float* gamma = (const float*)d_in[12];
    const float* beta = (const float*)d_in[13];
    float* out = (float*)d_out;

    float* ws = (float*)d_ws;
    ushort* h    = (ushort*)ws;                          // N*DIM us = 7,500,000 f
    ushort* A1h  = (ushort*)(ws + 7500000);              // MPAD*KP1 us = 8,007,680 f
    ushort* yh   = (ushort*)(ws + 15507680);             // MPAD*DIM2 us = 15,014,400 f
    ushort* Wt1  = (ushort*)(ws + 30522080);             // NP1*KP1 us = 102,400 f
    ushort* Wt2  = (ushort*)(ws + 30624480);             // NP2*KP2 us = 116,736 f
    ushort* bondh = (ushort*)(ws + 30741216);            // 48*DIM us = 7,200 f
    float* stats = ws + 30748416;                        // 3,600 f
    ushort* t1h  = (ushort*)(ws + 30752016);             // KP2 us = 304 f
    int* rowstart = (int*)(ws + 30752320);               // N+1
    int* deg      = rowstart + 50001;
    int* cursor   = deg + 50000;
    int2* epack   = (int2*)(cursor + 50000 + 1);         // align to 8B
    int* bsum     = (int*)(epack + 250000);              // SCAN_BLOCKS

    float* sum1 = stats;
    float* sq1  = stats + 600;
    float* sum2 = stats + 1200;
    float* sq2  = stats + 1500;
    float* scale1 = stats + 1800;
    float* shift1 = stats + 2400;
    float* scale2 = stats + 3000;
    float* shift2 = stats + 3300;

    const int PAIRS_N = N_NODES * (DIM / 2);

    // CSR build (once; edge_index is layer-invariant)
    hipMemsetAsync(deg, 0, 50000 * sizeof(int), stream);
    deg_count<<<(N_EDGES + 255) / 256, 256, 0, stream>>>(ei, deg);
    block_sums<<<SCAN_BLOCKS, 256, 0, stream>>>(deg, bsum);
    scan_bsums<<<1, 256, 0, stream>>>(bsum);
    write_rowstart<<<SCAN_BLOCKS, 256, 0, stream>>>(deg, bsum, rowstart, cursor);
    csr_fill<<<(N_EDGES + 255) / 256, 256, 0, stream>>>(ei, ea, cursor, epack);

    atom_enc<<<(PAIRS_N + 255) / 256, 256, 0, stream>>>(x, atom_emb, h);
    init_bn<<<(DIM + 255) / 256, 256, 0, stream>>>(scale2, shift2);

    for (int l = 0; l < NL; ++l) {
        hipMemsetAsync(stats, 0, 1800 * sizeof(float), stream);

        bond_conv<<<(48 * (DIM / 2) + 255) / 256, 256, 0, stream>>>(
            bond_emb + (size_t)l * 3 * 16 * DIM, bondh);

        agg_combine<<<(MPAD + 3) / 4, 256, 0, stream>>>(rowstart, epack, bondh,
                                                        h, scale2, shift2, (l > 0) ? 1 : 0,
                                                        eps, l, A1h);

        wt_conv<<<(KP1 * NP1 + 255) / 256, 256, 0, stream>>>(W1 + (size_t)l * DIM * DIM2, Wt1,
                                                             DIM, DIM2, KP1, NP1);

        gemm_mfma<<<(MPAD / 128) * (NP1 / 128), 256, 0, stream>>>(
            A1h, Wt1, b1 + l * DIM2, yh, N_NODES, KP1, DIM2, DIM2, NP1 / 128, sum1, sq1);

        bn_finalize<<<(KP2 + 255) / 256, 256, 0, stream>>>(sum1, sq1, g1 + l * DIM2,
                                                           be1 + l * DIM2, scale1, shift1,
                                                           t1h, DIM2, KP2);

        wt_conv2<<<(KP2 * NP2 + 255) / 256, 256, 0, stream>>>(W2 + (size_t)l * DIM2 * DIM,
                                                              scale1, Wt2);

        gemm2_fused<<<(MPAD / 128) * (NP2 / 128), 256, 0, stream>>>(
            yh, Wt2, t1h, b2 + l * DIM, h, sum2, sq2);

        bn_finalize<<<(DIM + 255) / 256, 256, 0, stream>>>(sum2, sq2, gamma + l * DIM,
                                                           beta + l * DIM, scale2, shift2,
                                                           nullptr, DIM, DIM);
    }

    // final output: BN2 of last layer, no ReLU
    bn_apply_out<<<(PAIRS_N + 255) / 256, 256, 0, stream>>>(h, scale2, shift2, out);
}

// Round 4
// 1098.321 us; speedup vs baseline: 2.8617x; 1.0561x over previous
//
#include <hip/hip_runtime.h>

#define N_NODES 50000
#define N_EDGES 250000
#define DIM 300
#define DIM2 600
#define NL 5
#define MPAD 50048      // 391 * 128
#define KP1 320         // DIM padded to mult of 32
#define KP2 608         // DIM2 padded to mult of 32
#define NP1 640         // DIM2 padded to mult of 128
#define NP2 384         // DIM padded to mult of 128
#define SCAN_BLOCKS 196 // ceil(N_NODES / 256)
#define CT_STRIDE 136   // 128 + 8 pad: breaks epilogue LDS write conflicts

typedef __attribute__((ext_vector_type(8))) _Float16 half8;
typedef __attribute__((ext_vector_type(2))) _Float16 half2v;
typedef __attribute__((ext_vector_type(8))) short short8;
typedef __attribute__((ext_vector_type(4))) float f32x4;
typedef unsigned short ushort;
typedef unsigned int uint;

#define AS1 __attribute__((address_space(1)))
#define AS3 __attribute__((address_space(3)))

// raw barrier with compiler memory fences: does NOT force a vmcnt drain
// (unlike __syncthreads), but pins plain loads/stores at IR level.
#define BARRIER() do { \
    asm volatile("" ::: "memory"); \
    __builtin_amdgcn_s_barrier(); \
    asm volatile("" ::: "memory"); \
} while (0)

static __device__ __forceinline__ ushort f2h(float f) {
    _Float16 h = (_Float16)f;
    return __builtin_bit_cast(ushort, h);
}
static __device__ __forceinline__ float h2f(ushort s) {
    return (float)__builtin_bit_cast(_Float16, s);
}
static __device__ __forceinline__ uint pk2(float a, float b) {
    return (uint)f2h(a) | ((uint)f2h(b) << 16);
}
static __device__ __forceinline__ half2v u2h2(uint u) {
    return __builtin_bit_cast(half2v, u);
}

// bijective XCD-contiguous remap (m204)
static __device__ __forceinline__ int xcd_swizzle(int o, int nwg) {
    int q = nwg >> 3, r = nwg & 7;
    int xcd = o & 7, idx = o >> 3;
    return (xcd < r ? xcd * (q + 1) : r * (q + 1) + (xcd - r) * q) + idx;
}

// ---------------- Atom encoder -> h fp16 ----------------
__global__ void atom_enc(const int* __restrict__ x, const float* __restrict__ emb,
                         ushort* __restrict__ h) {
    int idx = blockIdx.x * blockDim.x + threadIdx.x;  // pair index
    const int PAIRS = DIM / 2;  // 150
    if (idx >= N_NODES * PAIRS) return;
    int n = idx / PAIRS, p = idx - n * PAIRS;
    const int* xr = x + n * 9;
    float s0 = 0.f, s1 = 0.f;
#pragma unroll
    for (int i = 0; i < 9; i++) {
        const float2 v = *(const float2*)(emb + (size_t)(i * 128 + xr[i]) * DIM + 2 * p);
        s0 += v.x; s1 += v.y;
    }
    ((uint*)h)[idx] = pk2(s0, s1);
}

// ---------------- CSR build (once per launch; edge_index is layer-invariant) ----------
__global__ void deg_count(const int* __restrict__ ei, int* __restrict__ deg) {
    int e = blockIdx.x * blockDim.x + threadIdx.x;
    if (e < N_EDGES) atomicAdd(&deg[ei[N_EDGES + e]], 1);
}

__global__ void block_sums(const int* __restrict__ deg, int* __restrict__ bsum) {
    __shared__ int red[256];
    int tid = threadIdx.x;
    int node = blockIdx.x * 256 + tid;
    red[tid] = (node < N_NODES) ? deg[node] : 0;
    __syncthreads();
    for (int off = 128; off > 0; off >>= 1) {
        if (tid < off) red[tid] += red[tid + off];
        __syncthreads();
    }
    if (tid == 0) bsum[blockIdx.x] = red[0];
}

__global__ void scan_bsums(int* __restrict__ bsum) {
    __shared__ int s[256];
    int tid = threadIdx.x;
    int orig = (tid < SCAN_BLOCKS) ? bsum[tid] : 0;
    s[tid] = orig;
    __syncthreads();
    for (int off = 1; off < 256; off <<= 1) {
        int v = (tid >= off) ? s[tid - off] : 0;
        __syncthreads();
        s[tid] += v;
        __syncthreads();
    }
    if (tid < SCAN_BLOCKS) bsum[tid] = s[tid] - orig;  // exclusive
}

__global__ void write_rowstart(const int* __restrict__ deg, const int* __restrict__ bsum,
                               int* __restrict__ rowstart, int* __restrict__ cursor) {
    __shared__ int s[256];
    int tid = threadIdx.x;
    int node = blockIdx.x * 256 + tid;
    int d = (node < N_NODES) ? deg[node] : 0;
    s[tid] = d;
    __syncthreads();
    for (int off = 1; off < 256; off <<= 1) {
        int v = (tid >= off) ? s[tid - off] : 0;
        __syncthreads();
        s[tid] += v;
        __syncthreads();
    }
    int excl = s[tid] - d + bsum[blockIdx.x];
    if (node < N_NODES) {
        rowstart[node] = excl;
        cursor[node] = excl;
    }
    if (blockIdx.x == 0 && tid == 0) rowstart[N_NODES] = N_EDGES;
}

// fill CSR with pre-packed edge payload: (src, a0|a1<<8|a2<<16)
__global__ void csr_fill(const int* __restrict__ ei, const int* __restrict__ ea,
                         int* __restrict__ cursor, int2* __restrict__ epack) {
    int e = blockIdx.x * blockDim.x + threadIdx.x;
    if (e < N_EDGES) {
        int d = ei[N_EDGES + e];
        int slot = atomicAdd(&cursor[d], 1);
        int attr = ea[3 * e] | (ea[3 * e + 1] << 8) | (ea[3 * e + 2] << 16);
        epack[slot] = make_int2(ei[e], attr);
    }
}

// ---------------- per-layer bond table fp32 -> fp16 (28.8 KB, L1-resident) ----------
__global__ void bond_conv(const float* __restrict__ bond, ushort* __restrict__ bondh) {
    int idx = blockIdx.x * blockDim.x + threadIdx.x;  // pair index
    if (idx >= 48 * (DIM / 2)) return;
    float2 v = *(const float2*)(bond + 2 * idx);
    ((uint*)bondh)[idx] = pk2(v.x, v.y);
}

// ---------------- identity BN params for layer 0 ----------------
__global__ void init_bn(float* __restrict__ scale, float* __restrict__ shift) {
    int i = blockIdx.x * blockDim.x + threadIdx.x;
    if (i < DIM) { scale[i] = 1.f; shift[i] = 0.f; }
}

// ------- Fused BN2(+ReLU) on-load + gather-aggregate + GIN combine + fp16 cast --------
__launch_bounds__(256)
__global__ void agg_combine(const int* __restrict__ rowstart, const int2* __restrict__ epack,
                            const ushort* __restrict__ bondh, const ushort* __restrict__ h,
                            const float* __restrict__ scale, const float* __restrict__ shift,
                            int relu, const float* __restrict__ epsp, int layer,
                            ushort* __restrict__ A1) {
    int node = blockIdx.x * 4 + (threadIdx.x >> 6);
    int lane = threadIdx.x & 63;
    if (node >= MPAD) return;
    uint* row32 = (uint*)(A1 + (size_t)node * KP1);
    if (node >= N_NODES) {
        for (int i = lane; i < KP1 / 2; i += 64) row32[i] = 0;
        return;
    }
    const int PAIRS = DIM / 2;  // 150
    float2 scf[3], shf[3];
    half2v sch[3], shh[3];
#pragma unroll
    for (int i = 0; i < 3; i++) {
        int p = lane + 64 * i;
        scf[i] = make_float2(0.f, 0.f);
        shf[i] = make_float2(0.f, 0.f);
        if (p < PAIRS) {
            scf[i] = *(const float2*)(scale + 2 * p);
            shf[i] = *(const float2*)(shift + 2 * p);
        }
        sch[i] = half2v{(_Float16)scf[i].x, (_Float16)scf[i].y};
        shh[i] = half2v{(_Float16)shf[i].x, (_Float16)shf[i].y};
    }
    float epsv = 1.0f + epsp[layer];
    const uint* hd = (const uint*)(h + (size_t)node * DIM);
    float ax[3], ay[3];
#pragma unroll
    for (int i = 0; i < 3; i++) {
        int p = lane + 64 * i;
        ax[i] = 0.f; ay[i] = 0.f;
        if (p < PAIRS) {
            uint u = hd[p];
            float vx = h2f((ushort)(u & 0xffffu)) * scf[i].x + shf[i].x;
            float vy = h2f((ushort)(u >> 16)) * scf[i].y + shf[i].y;
            if (relu) { vx = fmaxf(vx, 0.f); vy = fmaxf(vy, 0.f); }
            ax[i] = epsv * vx; ay[i] = epsv * vy;
        }
    }

    auto edge_contrib = [&](int2 pk) {
        const uint* hs = (const uint*)(h + (size_t)pk.x * DIM);
        int a0 = pk.y & 0xff, a1v = (pk.y >> 8) & 0xff, a2 = (pk.y >> 16) & 0xff;
        const uint* t0 = (const uint*)(bondh + a0 * DIM);
        const uint* t1 = (const uint*)(bondh + (16 + a1v) * DIM);
        const uint* t2 = (const uint*)(bondh + (32 + a2) * DIM);
        const half2v z = {};
#pragma unroll
        for (int i = 0; i < 3; i++) {
            int p = lane + 64 * i;
            if (p < PAIRS) {
                half2v hv = u2h2(hs[p]) * sch[i] + shh[i];
                if (relu) hv = __builtin_elementwise_max(hv, z);
                half2v m = hv + u2h2(t0[p]) + u2h2(t1[p]) + u2h2(t2[p]);
                m = __builtin_elementwise_max(m, z);
                ax[i] += (float)m.x;
                ay[i] += (float)m.y;
            }
        }
    };

    int e0 = rowstart[node], e1 = rowstart[node + 1];
    int t = e0;
    for (; t + 1 < e1; t += 2) {
        int2 p0 = epack[t];
        int2 p1 = epack[t + 1];
        edge_contrib(p0);
        edge_contrib(p1);
    }
    if (t < e1) edge_contrib(epack[t]);

#pragma unroll
    for (int i = 0; i < 3; i++) {
        int p = lane + 64 * i;
        if (p < KP1 / 2) row32[p] = (p < PAIRS) ? pk2(ax[i], ay[i]) : 0u;
    }
}

// ---------------- W1 (K x N) -> Wt fp16 [NP x KP] transposed, zero-padded ----------
__global__ void wt_conv(const float* __restrict__ W, ushort* __restrict__ Wt,
                        int K, int Nc, int KP, int NP) {
    int idx = blockIdx.x * blockDim.x + threadIdx.x;
    if (idx >= KP * NP) return;
    int k = idx / NP, n = idx - k * NP;
    ushort v = 0;
    if (k < K && n < Nc) v = f2h(W[(size_t)k * Nc + n]);
    Wt[(size_t)n * KP + k] = v;
}

// ------- W2 with BN1 scale folded: Wt2[n][k] = fp16(scale1[k] * W2[k][n]) -------------
__global__ void wt_conv2(const float* __restrict__ W, const float* __restrict__ scale,
                         ushort* __restrict__ Wt) {
    int idx = blockIdx.x * blockDim.x + threadIdx.x;
    if (idx >= KP2 * NP2) return;
    int k = idx / NP2, n = idx - k * NP2;
    ushort v = 0;
    if (k < DIM2 && n < DIM) v = f2h(scale[k] * W[(size_t)k * DIM + n]);
    Wt[(size_t)n * KP2 + k] = v;
}

// ---------------- GEMM1: yh = A1 @ Wt1^T + b1, fp16 out + BN stats --------------------
// Depth-2 counted-vmcnt pipeline (T3+T4): stage(t+2) issued at step t; end-of-step wait
// vmcnt(4) keeps 4 glds in flight across barriers (never 0 in steady state).
// Per-step safety: frag-reads -> lgkmcnt(0) -> bar1 frees buf[t&1] before stage(t+2)
// overwrites it; vmcnt(4)+bar2 guarantees tile t+1 landed wave-wide before step t+1 reads.
// LDS: 4x8KB dbuf staging (As0,Bs0,As1,Bs1); epilogue C-half-tile (17.4KB) reuses it.
__launch_bounds__(256, 4)
__global__ void gemm_mfma(const ushort* __restrict__ A, const ushort* __restrict__ Wt,
                          const float* __restrict__ bias, ushort* __restrict__ Cout,
                          int M, int KP, int Nc, int strideC, int ntiles,
                          float* __restrict__ csum, float* __restrict__ csq) {
    __shared__ ushort smem[16384];  // 32 KB: As0@0 Bs0@4096 As1@8192 Bs1@12288 (elem offs)
    __shared__ float s_sum[128], s_sq[128];

    int tid = threadIdx.x;
    int w = tid >> 6, lane = tid & 63;
    int quad = lane >> 4, lr = lane & 15;
    int wm = w >> 1, wn = w & 1;
    int wg = xcd_swizzle(blockIdx.x, gridDim.x);
    int m0 = (wg / ntiles) * 128;
    int n0 = (wg % ntiles) * 128;

    if (tid < 128) { s_sum[tid] = 0.f; s_sq[tid] = 0.f; }

    // glds source chunk pre-swizzle (conflict-free ds_read_b128, verified 0 conflicts)
    const int kchunk = ((lane & 3) ^ ((lane >> 3) & 3)) * 8;
    const int grow = lane >> 2;
    const ushort* Abase = A + (size_t)m0 * KP + kchunk;
    const ushort* Bbase = Wt + (size_t)n0 * KP + kchunk;
    const int xq = (quad ^ ((lr >> 1) & 3)) * 8;  // matching swizzled read slot

    auto stage = [&](int k0, int buf) {  // 4 glds per wave (2 A + 2 B)
        ushort* dA = smem + buf * 8192;
#pragma unroll
        for (int c = w; c < 8; c += 4)
            __builtin_amdgcn_global_load_lds((const AS1 void*)(Abase + (size_t)(16 * c + grow) * KP + k0),
                                             (AS3 void*)(dA + c * 512), 16, 0, 0);
#pragma unroll
        for (int c = w; c < 8; c += 4)
            __builtin_amdgcn_global_load_lds((const AS1 void*)(Bbase + (size_t)(16 * c + grow) * KP + k0),
                                             (AS3 void*)(dA + 4096 + c * 512), 16, 0, 0);
    };

    f32x4 acc[4][4] = {};
    const int nk = KP >> 5;  // 10

    stage(0, 0);
    stage(32, 1);
    asm volatile("s_waitcnt vmcnt(4)" ::: "memory");  // tile 0 landed; tile 1 in flight
    BARRIER();

    for (int t = 0; t < nk; ++t) {
        const ushort* As = smem + (t & 1) * 8192;
        const ushort* Bs = As + 4096;
        half8 a[4], b[4];
#pragma unroll
        for (int mf = 0; mf < 4; mf++)
            a[mf] = __builtin_bit_cast(half8, *(const short8*)(As + (64 * wm + 16 * mf + lr) * 32 + xq));
#pragma unroll
        for (int nf = 0; nf < 4; nf++)
            b[nf] = __builtin_bit_cast(half8, *(const short8*)(Bs + (64 * wn + 16 * nf + lr) * 32 + xq));
        asm volatile("s_waitcnt lgkmcnt(0)" ::: "memory");  // reads complete -> buf free
        BARRIER();

        if (t + 2 < nk) stage((t + 2) << 5, t & 1);  // overwrite just-freed buffer

        __builtin_amdgcn_s_setprio(1);
#pragma unroll
        for (int mf = 0; mf < 4; mf++)
#pragma unroll
            for (int nf = 0; nf < 4; nf++)
                acc[mf][nf] = __builtin_amdgcn_mfma_f32_16x16x32_f16(a[mf], b[nf], acc[mf][nf], 0, 0, 0);
        __builtin_amdgcn_s_setprio(0);

        if (t + 2 < nk)       { asm volatile("s_waitcnt vmcnt(4)" ::: "memory"); }  // t+1 landed, t+2 in flight
        else if (t + 1 < nk)  { asm volatile("s_waitcnt vmcnt(0)" ::: "memory"); }  // tail drain (once)
        BARRIER();
    }

    // Epilogue: stats from regs + two 64-row half-tiles through LDS (reuses staging smem)
#pragma unroll
    for (int half = 0; half < 2; half++) {
        if (wm == half) {
#pragma unroll
            for (int nf = 0; nf < 4; nf++) {
                int lcol = 64 * wn + 16 * nf + lr;
                int gn = n0 + lcol;
                float bv = (gn < Nc) ? bias[gn] : 0.f;
                float ps = 0.f, pq = 0.f;
#pragma unroll
                for (int mf = 0; mf < 4; mf++) {
#pragma unroll
                    for (int r = 0; r < 4; r++) {
                        int lrow = 16 * mf + quad * 4 + r;  // 0..63 within half
                        float v = acc[mf][nf][r] + bv;
                        smem[lrow * CT_STRIDE + lcol] = f2h(v);
                        if (m0 + 64 * half + lrow < M && gn < Nc) { ps += v; pq += v * v; }
                    }
                }
                if (gn < Nc) {
                    atomicAdd(&s_sum[lcol], ps);
                    atomicAdd(&s_sq[lcol], pq);
                }
            }
        }
        __syncthreads();
        // coalesced readback: 64 rows x 16 chunks of 8 fp16 (16B)
#pragma unroll
        for (int it = 0; it < 4; it++) {
            int idx = tid + it * 256;
            int row = idx >> 4, ch = idx & 15;
            int gcol = n0 + ch * 8;
            if (gcol < Nc) {  // Nc=600 is 8-aligned: chunks fully in/out
                *(short8*)(Cout + (size_t)(m0 + 64 * half + row) * strideC + gcol) =
                    *(const short8*)(smem + row * CT_STRIDE + ch * 8);
            }
        }
        __syncthreads();
    }

    if (tid < 128) {
        int gn = n0 + tid;
        if (gn < Nc) {
            atomicAdd(&csum[gn], s_sum[tid]);
            atomicAdd(&csq[gn], s_sq[tid]);
        }
    }
}

// ------- GEMM2 with fused BN1 bias+ReLU A-staging: h = max(yh + t1h, 0) @ Wt2^T + b2 --
// Depth-2 counted pipeline for B (glds), depth-1 issue-early for y (reg-staged):
// y(t+1) issued at step-t top, transformed + ds_written to As[(t+1)&1] post-MFMA.
// The compiler's in-order vmcnt wait before the transform (y is older in the vmem queue
// than B(t+2)) also guarantees B(t+1) completion -- no explicit vmcnt needed in-loop.
__launch_bounds__(256, 4)
__global__ void gemm2_fused(const ushort* __restrict__ yh, const ushort* __restrict__ Wt,
                            const ushort* __restrict__ t1h, const float* __restrict__ bias,
                            ushort* __restrict__ hout,
                            float* __restrict__ csum, float* __restrict__ csq) {
    __shared__ ushort smem[16384];  // As0@0 Bs0@4096 As1@8192 Bs1@12288
    __shared__ ushort s_t[KP2];
    __shared__ float s_sum[128], s_sq[128];

    int tid = threadIdx.x;
    int w = tid >> 6, lane = tid & 63;
    int quad = lane >> 4, lr = lane & 15;
    int wm = w >> 1, wn = w & 1;
    int wg = xcd_swizzle(blockIdx.x, gridDim.x);
    int m0 = (wg / 3) * 128;
    int n0 = (wg % 3) * 128;

    int r0 = tid >> 2;          // 0..63; thread also handles r0+64
    int q = tid & 3;            // col-chunk index within 32
    int cc = q * 8;
    const int aslot = (q ^ ((r0 >> 1) & 3)) * 8;  // swizzled ds_write slot

    const int kchunk = ((lane & 3) ^ ((lane >> 3) & 3)) * 8;
    const int grow = lane >> 2;
    const ushort* Bbase = Wt + (size_t)n0 * KP2 + kchunk;
    const int xq = (quad ^ ((lr >> 1) & 3)) * 8;

    const ushort* yrow0 = yh + (size_t)(m0 + r0) * DIM2 + cc;
    const ushort* yrow1 = yh + (size_t)(m0 + r0 + 64) * DIM2 + cc;

    auto stageB = [&](int k0, int buf) {  // 2 glds per wave
        ushort* dB = smem + buf * 8192 + 4096;
#pragma unroll
        for (int c = w; c < 8; c += 4)
            __builtin_amdgcn_global_load_lds((const AS1 void*)(Bbase + (size_t)(16 * c + grow) * KP2 + k0),
                                             (AS3 void*)(dB + c * 512), 16, 0, 0);
    };

    if (tid < 128) { s_sum[tid] = 0.f; s_sq[tid] = 0.f; }

    // prologue: s_t, y(0), B(0), B(1)
    for (int i = tid; i < KP2 / 2; i += 256) ((uint*)s_t)[i] = ((const uint*)t1h)[i];
    half8 y0 = *(const half8*)(yrow0);
    half8 y1 = *(const half8*)(yrow1);
    stageB(0, 0);
    stageB(32, 1);
    asm volatile("s_waitcnt lgkmcnt(0)" ::: "memory");  // s_t ds_writes done
    BARRIER();
    {
        half8 z = {};
        half8 tt = *(const half8*)(s_t + cc);
        half8 a0 = __builtin_elementwise_max(y0 + tt, z);
        half8 a1 = __builtin_elementwise_max(y1 + tt, z);
        *(short8*)(smem + r0 * 32 + aslot) = __builtin_bit_cast(short8, a0);
        *(short8*)(smem + (r0 + 64) * 32 + aslot) = __builtin_bit_cast(short8, a1);
    }
    asm volatile("s_waitcnt vmcnt(2) lgkmcnt(0)" ::: "memory");  // B(0) landed + As0 written
    BARRIER();

    f32x4 acc[4][4] = {};
    const int nk = KP2 >> 5;  // 19

    for (int t = 0; t < nk; ++t) {
        // issue y(t+1) early: consumed post-MFMA (~400cy later)
        half8 yn0 = {}, yn1 = {};
        if (t + 1 < nk) {
            int coln = ((t + 1) << 5) + cc;
            if (coln < DIM2) {  // cols 600..607 are zero-pad: stay {}
                yn0 = *(const half8*)(yrow0 + ((t + 1) << 5));
                yn1 = *(const half8*)(yrow1 + ((t + 1) << 5));
            }
        }

        const ushort* As = smem + (t & 1) * 8192;
        const ushort* Bs = As + 4096;
        half8 a[4], b[4];
#pragma unroll
        for (int mf = 0; mf < 4; mf++)
            a[mf] = __builtin_bit_cast(half8, *(const short8*)(As + (64 * wm + 16 * mf + lr) * 32 + xq));
#pragma unroll
        for (int nf = 0; nf < 4; nf++)
            b[nf] = __builtin_bit_cast(half8, *(const short8*)(Bs + (64 * wn + 16 * nf + lr) * 32 + xq));
        asm volatile("s_waitcnt lgkmcnt(0)" ::: "memory");  // frag reads done -> buf free
        BARRIER();

        if (t + 2 < nk) stageB((t + 2) << 5, t & 1);

        __builtin_amdgcn_s_setprio(1);
#pragma unroll
        for (int mf = 0; mf < 4; mf++)
#pragma unroll
            for (int nf = 0; nf < 4; nf++)
                acc[mf][nf] = __builtin_amdgcn_mfma_f32_16x16x32_f16(a[mf], b[nf], acc[mf][nf], 0, 0, 0);
        __builtin_amdgcn_s_setprio(0);

        if (t + 1 < nk) {
            // implicit compiler vmcnt before yn use drains B(t+1) too (in-order queue)
            half8 z = {};
            half8 tt = *(const half8*)(s_t + ((t + 1) << 5) + cc);  // zero-padded past 600
            half8 a0 = __builtin_elementwise_max(yn0 + tt, z);
            half8 a1 = __builtin_elementwise_max(yn1 + tt, z);
            ushort* Anx = smem + ((t + 1) & 1) * 8192;
            *(short8*)(Anx + r0 * 32 + aslot) = __builtin_bit_cast(short8, a0);
            *(short8*)(Anx + (r0 + 64) * 32 + aslot) = __builtin_bit_cast(short8, a1);
        }
        asm volatile("s_waitcnt lgkmcnt(0)" ::: "memory");  // A(t+1) ds_writes visible
        BARRIER();
    }

    // Epilogue: stats from regs + two 64-row half-tiles through LDS
#pragma unroll
    for (int half = 0; half < 2; half++) {
        if (wm == half) {
#pragma unroll
            for (int nf = 0; nf < 4; nf++) {
                int lcol = 64 * wn + 16 * nf + lr;
                int gn = n0 + lcol;
                float bv = (gn < DIM) ? bias[gn] : 0.f;
                float ps = 0.f, pq = 0.f;
#pragma unroll
                for (int mf = 0; mf < 4; mf++) {
#pragma unroll
                    for (int r = 0; r < 4; r++) {
                        int lrow = 16 * mf + quad * 4 + r;  // 0..63 within half
                        float v = acc[mf][nf][r] + bv;
                        smem[lrow * CT_STRIDE + lcol] = f2h(v);
                        if (m0 + 64 * half + lrow < N_NODES && gn < DIM) { ps += v; pq += v * v; }
                    }
                }
                if (gn < DIM) {
                    atomicAdd(&s_sum[lcol], ps);
                    atomicAdd(&s_sq[lcol], pq);
                }
            }
        }
        __syncthreads();
        // coalesced readback: 64 rows x 32 chunks of 4 fp16 (8B); DIM=300 is 4-aligned
#pragma unroll
        for (int it = 0; it < 8; it++) {
            int idx = tid + it * 256;
            int row = idx >> 5, ch = idx & 31;
            int gm = m0 + 64 * half + row, gcol = n0 + ch * 4;
            if (gm < N_NODES && gcol < DIM) {
                *(uint2*)(hout + (size_t)gm * DIM + gcol) =
                    *(const uint2*)(smem + row * CT_STRIDE + ch * 4);
            }
        }
        __syncthreads();
    }

    if (tid < 128) {
        int gn = n0 + tid;
        if (gn < DIM) {
            atomicAdd(&csum[gn], s_sum[tid]);
            atomicAdd(&csq[gn], s_sq[tid]);
        }
    }
}

// ---------------- BN stats -> per-column scale/shift (+optional fp16 t' = shift/scale) -
__global__ void bn_finalize(const float* __restrict__ sum, const float* __restrict__ sq,
                            const float* __restrict__ g, const float* __restrict__ b,
                            float* __restrict__ scale, float* __restrict__ shift,
                            ushort* __restrict__ th, int n, int npad) {
    int i = blockIdx.x * blockDim.x + threadIdx.x;
    if (i >= n) {
        if (th && i < npad) th[i] = 0;
        return;
    }
    const float invN = 1.0f / (float)N_NODES;
    float m = sum[i] * invN;
    float v = sq[i] * invN - m * m;
    float inv = rsqrtf(v + 1e-5f);
    float sc = g[i] * inv;
    scale[i] = sc;
    shift[i] = b[i] - m * sc;
    if (th) th[i] = f2h((b[i] - m * sc) / sc);  // scale > 0 (g1 = ones)
}

// ---------------- Final output: BN2 of last layer from fp16 h -> fp32 out -------------
__global__ void bn_apply_out(const ushort* __restrict__ h, const float* __restrict__ scale,
                             const float* __restrict__ shift, float* __restrict__ out) {
    int idx = blockIdx.x * blockDim.x + threadIdx.x;  // pair index
    const int PAIRS = DIM / 2;
    if (idx >= N_NODES * PAIRS) return;
    int p = idx % PAIRS;
    uint u = ((const uint*)h)[idx];
    float2 sc = *(const float2*)(scale + 2 * p);
    float2 sh = *(const float2*)(shift + 2 * p);
    float2 o;
    o.x = h2f((ushort)(u & 0xffffu)) * sc.x + sh.x;
    o.y = h2f((ushort)(u >> 16)) * sc.y + sh.y;
    *(float2*)(out + 2 * idx) = o;
}

extern "C" void kernel_launch(void* const* d_in, const int* in_sizes, int n_in,
                              void* d_out, int out_size, void* d_ws, size_t ws_size,
                              hipStream_t stream) {
    const int* x = (const int*)d_in[0];
    const int* ei = (const int*)d_in[1];
    const int* ea = (const int*)d_in[2];
    const float* atom_emb = (const float*)d_in[3];
    const float* bond_emb = (const float*)d_in[4];
    const float* eps = (const float*)d_in[5];
    const float* W1 = (const float*)d_in[6];
    const float* b1 = (const float*)d_in[7];
    const float* g1 = (const float*)d_in[8];
    const float* be1 = (const float*)d_in[9];
    const float* W2 = (const float*)d_in[10];
    const float* b2 = (const float*)d_in[11];
    const float* gamma = (const float*)d_in[12];
    const float* beta = (const float*)d_in[13];
    float* out = (float*)d_out;

    float* ws = (float*)d_ws;
    ushort* h    = (ushort*)ws;                          // N*DIM us = 7,500,000 f
    ushort* A1h  = (ushort*)(ws + 7500000);              // MPAD*KP1 us = 8,007,680 f
    ushort* yh   = (ushort*)(ws + 15507680);             // MPAD*DIM2 us = 15,014,400 f
    ushort* Wt1  = (ushort*)(ws + 30522080);             // NP1*KP1 us = 102,400 f
    ushort* Wt2  = (ushort*)(ws + 30624480);             // NP2*KP2 us = 116,736 f
    ushort* bondh = (ushort*)(ws + 30741216);            // 48*DIM us = 7,200 f
    float* stats = ws + 30748416;                        // 3,600 f
    ushort* t1h  = (ushort*)(ws + 30752016);             // KP2 us = 304 f
    int* rowstart = (int*)(ws + 30752320);               // N+1
    int* deg      = rowstart + 50001;
    int* cursor   = deg + 50000;
    int2* epack   = (int2*)(cursor + 50000 + 1);         // align to 8B
    int* bsum     = (int*)(epack + 250000);              // SCAN_BLOCKS

    float* sum1 = stats;
    float* sq1  = stats + 600;
    float* sum2 = stats + 1200;
    float* sq2  = stats + 1500;
    float* scale1 = stats + 1800;
    float* shift1 = stats + 2400;
    float* scale2 = stats + 3000;
    float* shift2 = stats + 3300;

    const int PAIRS_N = N_NODES * (DIM / 2);

    // CSR build (once; edge_index is layer-invariant)
    hipMemsetAsync(deg, 0, 50000 * sizeof(int), stream);
    deg_count<<<(N_EDGES + 255) / 256, 256, 0, stream>>>(ei, deg);
    block_sums<<<SCAN_BLOCKS, 256, 0, stream>>>(deg, bsum);
    scan_bsums<<<1, 256, 0, stream>>>(bsum);
    write_rowstart<<<SCAN_BLOCKS, 256, 0, stream>>>(deg, bsum, rowstart, cursor);
    csr_fill<<<(N_EDGES + 255) / 256, 256, 0, stream>>>(ei, ea, cursor, epack);

    atom_enc<<<(PAIRS_N + 255) / 256, 256, 0, stream>>>(x, atom_emb, h);
    init_bn<<<(DIM + 255) / 256, 256, 0, stream>>>(scale2, shift2);

    for (int l = 0; l < NL; ++l) {
        hipMemsetAsync(stats, 0, 1800 * sizeof(float), stream);

        bond_conv<<<(48 * (DIM / 2) + 255) / 256, 256, 0, stream>>>(
            bond_emb + (size_t)l * 3 * 16 * DIM, bondh);

        agg_combine<<<(MPAD + 3) / 4, 256, 0, stream>>>(rowstart, epack, bondh,
                                                        h, scale2, shift2, (l > 0) ? 1 : 0,
                                                        eps, l, A1h);

        wt_conv<<<(KP1 * NP1 + 255) / 256, 256, 0, stream>>>(W1 + (size_t)l * DIM * DIM2, Wt1,
                                                             DIM, DIM2, KP1, NP1);

        gemm_mfma<<<(MPAD / 128) * (NP1 / 128), 256, 0, stream>>>(
            A1h, Wt1, b1 + l * DIM2, yh, N_NODES, KP1, DIM2, DIM2, NP1 / 128, sum1, sq1);

        bn_finalize<<<(KP2 + 255) / 256, 256, 0, stream>>>(sum1, sq1, g1 + l * DIM2,
                                                           be1 + l * DIM2, scale1, shift1,
                                                           t1h, DIM2, KP2);

        wt_conv2<<<(KP2 * NP2 + 255) / 256, 256, 0, stream>>>(W2 + (size_t)l * DIM2 * DIM,
                                                              scale1, Wt2);

        gemm2_fused<<<(MPAD / 128) * (NP2 / 128), 256, 0, stream>>>(
            yh, Wt2, t1h, b2 + l * DIM, h, sum2, sq2);

        bn_finalize<<<(DIM + 255) / 256, 256, 0, stream>>>(sum2, sq2, gamma + l * DIM,
                                                           beta + l * DIM, scale2, shift2,
                                                           nullptr, DIM, DIM);
    }

    // final output: BN2 of last layer, no ReLU
    bn_apply_out<<<(PAIRS_N + 255) / 256, 256, 0, stream>>>(h, scale2, shift2, out);
}

// Round 5
// 1090.428 us; speedup vs baseline: 2.8825x; 1.0072x over previous
//
#include <hip/hip_runtime.h>

#define N_NODES 50000
#define N_EDGES 250000
#define DIM 300
#define DIM2 600
#define NL 5
#define MPAD 50048      // 391 * 128
#define KP1 320         // DIM padded to mult of 32
#define KP2 608         // DIM2 padded to mult of 32
#define NP1 640         // DIM2 padded to mult of 128
#define NP2 384         // DIM padded to mult of 128
#define SCAN_BLOCKS 196 // ceil(N_NODES / 256)
#define CT_STRIDE 136   // 128 + 8 pad: breaks epilogue LDS write conflicts

typedef __attribute__((ext_vector_type(8))) _Float16 half8;
typedef __attribute__((ext_vector_type(2))) _Float16 half2v;
typedef __attribute__((ext_vector_type(8))) short short8;
typedef __attribute__((ext_vector_type(4))) float f32x4;
typedef unsigned short ushort;
typedef unsigned int uint;

#define AS1 __attribute__((address_space(1)))
#define AS3 __attribute__((address_space(3)))

// raw barrier with compiler memory fences: does NOT force a vmcnt drain
// (unlike __syncthreads), but pins plain loads/stores at IR level.
#define BARRIER() do { \
    asm volatile("" ::: "memory"); \
    __builtin_amdgcn_s_barrier(); \
    asm volatile("" ::: "memory"); \
} while (0)

static __device__ __forceinline__ ushort f2h(float f) {
    _Float16 h = (_Float16)f;
    return __builtin_bit_cast(ushort, h);
}
static __device__ __forceinline__ float h2f(ushort s) {
    return (float)__builtin_bit_cast(_Float16, s);
}
static __device__ __forceinline__ uint pk2(float a, float b) {
    return (uint)f2h(a) | ((uint)f2h(b) << 16);
}
static __device__ __forceinline__ half2v u2h2(uint u) {
    return __builtin_bit_cast(half2v, u);
}

// bijective XCD-contiguous remap (m204)
static __device__ __forceinline__ int xcd_swizzle(int o, int nwg) {
    int q = nwg >> 3, r = nwg & 7;
    int xcd = o & 7, idx = o >> 3;
    return (xcd < r ? xcd * (q + 1) : r * (q + 1) + (xcd - r) * q) + idx;
}

// ---------------- Atom encoder -> h fp16 ----------------
__global__ void atom_enc(const int* __restrict__ x, const float* __restrict__ emb,
                         ushort* __restrict__ h) {
    int idx = blockIdx.x * blockDim.x + threadIdx.x;  // pair index
    const int PAIRS = DIM / 2;  // 150
    if (idx >= N_NODES * PAIRS) return;
    int n = idx / PAIRS, p = idx - n * PAIRS;
    const int* xr = x + n * 9;
    float s0 = 0.f, s1 = 0.f;
#pragma unroll
    for (int i = 0; i < 9; i++) {
        const float2 v = *(const float2*)(emb + (size_t)(i * 128 + xr[i]) * DIM + 2 * p);
        s0 += v.x; s1 += v.y;
    }
    ((uint*)h)[idx] = pk2(s0, s1);
}

// ---------------- CSR build (once per launch; edge_index is layer-invariant) ----------
__global__ void deg_count(const int* __restrict__ ei, int* __restrict__ deg) {
    int e = blockIdx.x * blockDim.x + threadIdx.x;
    if (e < N_EDGES) atomicAdd(&deg[ei[N_EDGES + e]], 1);
}

__global__ void block_sums(const int* __restrict__ deg, int* __restrict__ bsum) {
    __shared__ int red[256];
    int tid = threadIdx.x;
    int node = blockIdx.x * 256 + tid;
    red[tid] = (node < N_NODES) ? deg[node] : 0;
    __syncthreads();
    for (int off = 128; off > 0; off >>= 1) {
        if (tid < off) red[tid] += red[tid + off];
        __syncthreads();
    }
    if (tid == 0) bsum[blockIdx.x] = red[0];
}

__global__ void scan_bsums(int* __restrict__ bsum) {
    __shared__ int s[256];
    int tid = threadIdx.x;
    int orig = (tid < SCAN_BLOCKS) ? bsum[tid] : 0;
    s[tid] = orig;
    __syncthreads();
    for (int off = 1; off < 256; off <<= 1) {
        int v = (tid >= off) ? s[tid - off] : 0;
        __syncthreads();
        s[tid] += v;
        __syncthreads();
    }
    if (tid < SCAN_BLOCKS) bsum[tid] = s[tid] - orig;  // exclusive
}

__global__ void write_rowstart(const int* __restrict__ deg, const int* __restrict__ bsum,
                               int* __restrict__ rowstart, int* __restrict__ cursor) {
    __shared__ int s[256];
    int tid = threadIdx.x;
    int node = blockIdx.x * 256 + tid;
    int d = (node < N_NODES) ? deg[node] : 0;
    s[tid] = d;
    __syncthreads();
    for (int off = 1; off < 256; off <<= 1) {
        int v = (tid >= off) ? s[tid - off] : 0;
        __syncthreads();
        s[tid] += v;
        __syncthreads();
    }
    int excl = s[tid] - d + bsum[blockIdx.x];
    if (node < N_NODES) {
        rowstart[node] = excl;
        cursor[node] = excl;
    }
    if (blockIdx.x == 0 && tid == 0) rowstart[N_NODES] = N_EDGES;
}

// fill CSR with pre-packed edge payload: (src, a0|a1<<8|a2<<16)
__global__ void csr_fill(const int* __restrict__ ei, const int* __restrict__ ea,
                         int* __restrict__ cursor, int2* __restrict__ epack) {
    int e = blockIdx.x * blockDim.x + threadIdx.x;
    if (e < N_EDGES) {
        int d = ei[N_EDGES + e];
        int slot = atomicAdd(&cursor[d], 1);
        int attr = ea[3 * e] | (ea[3 * e + 1] << 8) | (ea[3 * e + 2] << 16);
        epack[slot] = make_int2(ei[e], attr);
    }
}

// ---------------- per-layer bond table fp32 -> fp16 (28.8 KB, L1-resident) ----------
__global__ void bond_conv(const float* __restrict__ bond, ushort* __restrict__ bondh) {
    int idx = blockIdx.x * blockDim.x + threadIdx.x;  // pair index
    if (idx >= 48 * (DIM / 2)) return;
    float2 v = *(const float2*)(bond + 2 * idx);
    ((uint*)bondh)[idx] = pk2(v.x, v.y);
}

// ---------------- identity BN params for layer 0 ----------------
__global__ void init_bn(float* __restrict__ scale, float* __restrict__ shift) {
    int i = blockIdx.x * blockDim.x + threadIdx.x;
    if (i < DIM) { scale[i] = 1.f; shift[i] = 0.f; }
}

// ------- Fused BN2(+ReLU) on-load + gather-aggregate + GIN combine + fp16 cast --------
__launch_bounds__(256)
__global__ void agg_combine(const int* __restrict__ rowstart, const int2* __restrict__ epack,
                            const ushort* __restrict__ bondh, const ushort* __restrict__ h,
                            const float* __restrict__ scale, const float* __restrict__ shift,
                            int relu, const float* __restrict__ epsp, int layer,
                            ushort* __restrict__ A1) {
    int node = blockIdx.x * 4 + (threadIdx.x >> 6);
    int lane = threadIdx.x & 63;
    if (node >= MPAD) return;
    uint* row32 = (uint*)(A1 + (size_t)node * KP1);
    if (node >= N_NODES) {
        for (int i = lane; i < KP1 / 2; i += 64) row32[i] = 0;
        return;
    }
    const int PAIRS = DIM / 2;  // 150
    float2 scf[3], shf[3];
    half2v sch[3], shh[3];
#pragma unroll
    for (int i = 0; i < 3; i++) {
        int p = lane + 64 * i;
        scf[i] = make_float2(0.f, 0.f);
        shf[i] = make_float2(0.f, 0.f);
        if (p < PAIRS) {
            scf[i] = *(const float2*)(scale + 2 * p);
            shf[i] = *(const float2*)(shift + 2 * p);
        }
        sch[i] = half2v{(_Float16)scf[i].x, (_Float16)scf[i].y};
        shh[i] = half2v{(_Float16)shf[i].x, (_Float16)shf[i].y};
    }
    float epsv = 1.0f + epsp[layer];
    const uint* hd = (const uint*)(h + (size_t)node * DIM);
    float ax[3], ay[3];
#pragma unroll
    for (int i = 0; i < 3; i++) {
        int p = lane + 64 * i;
        ax[i] = 0.f; ay[i] = 0.f;
        if (p < PAIRS) {
            uint u = hd[p];
            float vx = h2f((ushort)(u & 0xffffu)) * scf[i].x + shf[i].x;
            float vy = h2f((ushort)(u >> 16)) * scf[i].y + shf[i].y;
            if (relu) { vx = fmaxf(vx, 0.f); vy = fmaxf(vy, 0.f); }
            ax[i] = epsv * vx; ay[i] = epsv * vy;
        }
    }

    auto edge_contrib = [&](int2 pk) {
        const uint* hs = (const uint*)(h + (size_t)pk.x * DIM);
        int a0 = pk.y & 0xff, a1v = (pk.y >> 8) & 0xff, a2 = (pk.y >> 16) & 0xff;
        const uint* t0 = (const uint*)(bondh + a0 * DIM);
        const uint* t1 = (const uint*)(bondh + (16 + a1v) * DIM);
        const uint* t2 = (const uint*)(bondh + (32 + a2) * DIM);
        const half2v z = {};
#pragma unroll
        for (int i = 0; i < 3; i++) {
            int p = lane + 64 * i;
            if (p < PAIRS) {
                half2v hv = u2h2(hs[p]) * sch[i] + shh[i];
                if (relu) hv = __builtin_elementwise_max(hv, z);
                half2v m = hv + u2h2(t0[p]) + u2h2(t1[p]) + u2h2(t2[p]);
                m = __builtin_elementwise_max(m, z);
                ax[i] += (float)m.x;
                ay[i] += (float)m.y;
            }
        }
    };

    int e0 = rowstart[node], e1 = rowstart[node + 1];
    int t = e0;
    for (; t + 1 < e1; t += 2) {
        int2 p0 = epack[t];
        int2 p1 = epack[t + 1];
        edge_contrib(p0);
        edge_contrib(p1);
    }
    if (t < e1) edge_contrib(epack[t]);

#pragma unroll
    for (int i = 0; i < 3; i++) {
        int p = lane + 64 * i;
        if (p < KP1 / 2) row32[p] = (p < PAIRS) ? pk2(ax[i], ay[i]) : 0u;
    }
}

// ---------------- W1 (K x N) -> Wt fp16 [NP x KP] transposed, zero-padded ----------
__global__ void wt_conv(const float* __restrict__ W, ushort* __restrict__ Wt,
                        int K, int Nc, int KP, int NP) {
    int idx = blockIdx.x * blockDim.x + threadIdx.x;
    if (idx >= KP * NP) return;
    int k = idx / NP, n = idx - k * NP;
    ushort v = 0;
    if (k < K && n < Nc) v = f2h(W[(size_t)k * Nc + n]);
    Wt[(size_t)n * KP + k] = v;
}

// ------- W2 with BN1 scale folded: Wt2[n][k] = fp16(scale1[k] * W2[k][n]) -------------
__global__ void wt_conv2(const float* __restrict__ W, const float* __restrict__ scale,
                         ushort* __restrict__ Wt) {
    int idx = blockIdx.x * blockDim.x + threadIdx.x;
    if (idx >= KP2 * NP2) return;
    int k = idx / NP2, n = idx - k * NP2;
    ushort v = 0;
    if (k < DIM2 && n < DIM) v = f2h(scale[k] * W[(size_t)k * DIM + n]);
    Wt[(size_t)n * KP2 + k] = v;
}

// ---------------- GEMM1: yh = A1 @ Wt1^T + b1, fp16 out + BN stats --------------------
// (unchanged from R4 — depth-2 counted pipeline; it improved there)
__launch_bounds__(256, 4)
__global__ void gemm_mfma(const ushort* __restrict__ A, const ushort* __restrict__ Wt,
                          const float* __restrict__ bias, ushort* __restrict__ Cout,
                          int M, int KP, int Nc, int strideC, int ntiles,
                          float* __restrict__ csum, float* __restrict__ csq) {
    __shared__ ushort smem[16384];  // 32 KB: As0@0 Bs0@4096 As1@8192 Bs1@12288 (elem offs)
    __shared__ float s_sum[128], s_sq[128];

    int tid = threadIdx.x;
    int w = tid >> 6, lane = tid & 63;
    int quad = lane >> 4, lr = lane & 15;
    int wm = w >> 1, wn = w & 1;
    int wg = xcd_swizzle(blockIdx.x, gridDim.x);
    int m0 = (wg / ntiles) * 128;
    int n0 = (wg % ntiles) * 128;

    if (tid < 128) { s_sum[tid] = 0.f; s_sq[tid] = 0.f; }

    // glds source chunk pre-swizzle (conflict-free ds_read_b128, verified 0 conflicts)
    const int kchunk = ((lane & 3) ^ ((lane >> 3) & 3)) * 8;
    const int grow = lane >> 2;
    const ushort* Abase = A + (size_t)m0 * KP + kchunk;
    const ushort* Bbase = Wt + (size_t)n0 * KP + kchunk;
    const int xq = (quad ^ ((lr >> 1) & 3)) * 8;  // matching swizzled read slot

    auto stage = [&](int k0, int buf) {  // 4 glds per wave (2 A + 2 B)
        ushort* dA = smem + buf * 8192;
#pragma unroll
        for (int c = w; c < 8; c += 4)
            __builtin_amdgcn_global_load_lds((const AS1 void*)(Abase + (size_t)(16 * c + grow) * KP + k0),
                                             (AS3 void*)(dA + c * 512), 16, 0, 0);
#pragma unroll
        for (int c = w; c < 8; c += 4)
            __builtin_amdgcn_global_load_lds((const AS1 void*)(Bbase + (size_t)(16 * c + grow) * KP + k0),
                                             (AS3 void*)(dA + 4096 + c * 512), 16, 0, 0);
    };

    f32x4 acc[4][4] = {};
    const int nk = KP >> 5;  // 10

    stage(0, 0);
    stage(32, 1);
    asm volatile("s_waitcnt vmcnt(4)" ::: "memory");  // tile 0 landed; tile 1 in flight
    BARRIER();

    for (int t = 0; t < nk; ++t) {
        const ushort* As = smem + (t & 1) * 8192;
        const ushort* Bs = As + 4096;
        half8 a[4], b[4];
#pragma unroll
        for (int mf = 0; mf < 4; mf++)
            a[mf] = __builtin_bit_cast(half8, *(const short8*)(As + (64 * wm + 16 * mf + lr) * 32 + xq));
#pragma unroll
        for (int nf = 0; nf < 4; nf++)
            b[nf] = __builtin_bit_cast(half8, *(const short8*)(Bs + (64 * wn + 16 * nf + lr) * 32 + xq));
        asm volatile("s_waitcnt lgkmcnt(0)" ::: "memory");  // reads complete -> buf free
        BARRIER();

        if (t + 2 < nk) stage((t + 2) << 5, t & 1);  // overwrite just-freed buffer

        __builtin_amdgcn_s_setprio(1);
#pragma unroll
        for (int mf = 0; mf < 4; mf++)
#pragma unroll
            for (int nf = 0; nf < 4; nf++)
                acc[mf][nf] = __builtin_amdgcn_mfma_f32_16x16x32_f16(a[mf], b[nf], acc[mf][nf], 0, 0, 0);
        __builtin_amdgcn_s_setprio(0);

        if (t + 2 < nk)       { asm volatile("s_waitcnt vmcnt(4)" ::: "memory"); }  // t+1 landed, t+2 in flight
        else if (t + 1 < nk)  { asm volatile("s_waitcnt vmcnt(0)" ::: "memory"); }  // tail drain (once)
        BARRIER();
    }

    // Epilogue: stats from regs + two 64-row half-tiles through LDS (reuses staging smem)
#pragma unroll
    for (int half = 0; half < 2; half++) {
        if (wm == half) {
#pragma unroll
            for (int nf = 0; nf < 4; nf++) {
                int lcol = 64 * wn + 16 * nf + lr;
                int gn = n0 + lcol;
                float bv = (gn < Nc) ? bias[gn] : 0.f;
                float ps = 0.f, pq = 0.f;
#pragma unroll
                for (int mf = 0; mf < 4; mf++) {
#pragma unroll
                    for (int r = 0; r < 4; r++) {
                        int lrow = 16 * mf + quad * 4 + r;  // 0..63 within half
                        float v = acc[mf][nf][r] + bv;
                        smem[lrow * CT_STRIDE + lcol] = f2h(v);
                        if (m0 + 64 * half + lrow < M && gn < Nc) { ps += v; pq += v * v; }
                    }
                }
                if (gn < Nc) {
                    atomicAdd(&s_sum[lcol], ps);
                    atomicAdd(&s_sq[lcol], pq);
                }
            }
        }
        __syncthreads();
        // coalesced readback: 64 rows x 16 chunks of 8 fp16 (16B)
#pragma unroll
        for (int it = 0; it < 4; it++) {
            int idx = tid + it * 256;
            int row = idx >> 4, ch = idx & 15;
            int gcol = n0 + ch * 8;
            if (gcol < Nc) {  // Nc=600 is 8-aligned: chunks fully in/out
                *(short8*)(Cout + (size_t)(m0 + 64 * half + row) * strideC + gcol) =
                    *(const short8*)(smem + row * CT_STRIDE + ch * 8);
            }
        }
        __syncthreads();
    }

    if (tid < 128) {
        int gn = n0 + tid;
        if (gn < Nc) {
            atomicAdd(&csum[gn], s_sum[tid]);
            atomicAdd(&csq[gn], s_sq[tid]);
        }
    }
}

// ------- GEMM2 with fused BN1 bias+ReLU A-staging: h = max(yh + t1h, 0) @ Wt2^T + b2 --
// ONE barrier per K-step (R1's winning shape) + true counted depth via 3 rotating B
// buffers: stageB(t+2) never targets a live buffer, so no read-fence barrier is needed.
// No explicit in-loop vmcnt: the compiler's register-dep wait for y(t+1) at the
// transform (y issued BEFORE stageB(t+2) -> vmcnt(2)) transitively drains B(t+1)
// via the in-order vmem queue; only B(t+2) stays in flight across the barrier.
// LDS: As0@0 As1@4096 Bs0@8192 Bs1@12288 Bs2@16384 (ushort idx) = 40 KB.
__launch_bounds__(256, 4)
__global__ void gemm2_fused(const ushort* __restrict__ yh, const ushort* __restrict__ Wt,
                            const ushort* __restrict__ t1h, const float* __restrict__ bias,
                            ushort* __restrict__ hout,
                            float* __restrict__ csum, float* __restrict__ csq) {
    __shared__ ushort smem[20480];  // 40 KB staging; epilogue C-half-tile (8704 us) reuses
    __shared__ ushort s_t[KP2];
    __shared__ float s_sum[128], s_sq[128];

    int tid = threadIdx.x;
    int w = tid >> 6, lane = tid & 63;
    int quad = lane >> 4, lr = lane & 15;
    int wm = w >> 1, wn = w & 1;
    int wg = xcd_swizzle(blockIdx.x, gridDim.x);
    int m0 = (wg / 3) * 128;
    int n0 = (wg % 3) * 128;

    int r0 = tid >> 2;          // 0..63; thread also handles r0+64
    int q = tid & 3;            // col-chunk index within 32
    int cc = q * 8;
    const int aslot = (q ^ ((r0 >> 1) & 3)) * 8;  // swizzled ds_write slot

    const int kchunk = ((lane & 3) ^ ((lane >> 3) & 3)) * 8;
    const int grow = lane >> 2;
    const ushort* Bbase = Wt + (size_t)n0 * KP2 + kchunk;
    const int xq = (quad ^ ((lr >> 1) & 3)) * 8;

    const ushort* yrow0 = yh + (size_t)(m0 + r0) * DIM2 + cc;
    const ushort* yrow1 = yh + (size_t)(m0 + r0 + 64) * DIM2 + cc;

    auto stageB = [&](int k0, int buf) {  // 2 glds per wave; buf in 0..2
        ushort* dB = smem + 8192 + buf * 4096;
#pragma unroll
        for (int c = w; c < 8; c += 4)
            __builtin_amdgcn_global_load_lds((const AS1 void*)(Bbase + (size_t)(16 * c + grow) * KP2 + k0),
                                             (AS3 void*)(dB + c * 512), 16, 0, 0);
    };

    if (tid < 128) { s_sum[tid] = 0.f; s_sq[tid] = 0.f; }

    // prologue: s_t, y(0), B(0)->Bs0, B(1)->Bs1
    for (int i = tid; i < KP2 / 2; i += 256) ((uint*)s_t)[i] = ((const uint*)t1h)[i];
    half8 y0 = *(const half8*)(yrow0);   // y(0) issued BEFORE stageB: its wait won't drain B
    half8 y1 = *(const half8*)(yrow1);
    stageB(0, 0);
    stageB(32, 1);
    asm volatile("s_waitcnt lgkmcnt(0)" ::: "memory");  // s_t ds_writes done
    BARRIER();                                          // s_t visible to all waves
    {
        half8 z = {};
        half8 tt = *(const half8*)(s_t + cc);
        half8 a0 = __builtin_elementwise_max(y0 + tt, z);  // compiler: vmcnt(4) for y(0)
        half8 a1 = __builtin_elementwise_max(y1 + tt, z);
        *(short8*)(smem + r0 * 32 + aslot) = __builtin_bit_cast(short8, a0);
        *(short8*)(smem + (r0 + 64) * 32 + aslot) = __builtin_bit_cast(short8, a1);
    }
    asm volatile("s_waitcnt vmcnt(2) lgkmcnt(0)" ::: "memory");  // B(0) landed; As0 written
    BARRIER();

    f32x4 acc[4][4] = {};
    const int nk = KP2 >> 5;  // 19

    for (int t = 0; t < nk; ++t) {
        // issue y(t+1) first (so its wait leaves B(t+2) in flight), then B(t+2)
        half8 yn0 = {}, yn1 = {};
        int coln = ((t + 1) << 5) + cc;
        if (t + 1 < nk && coln < DIM2) {  // cols 600..607 are zero-pad: stay {}
            yn0 = *(const half8*)(yrow0 + ((t + 1) << 5));
            yn1 = *(const half8*)(yrow1 + ((t + 1) << 5));
        }
        if (t + 2 < nk) stageB((t + 2) << 5, (t + 2) % 3);

        const ushort* As = smem + (t & 1) * 4096;
        const ushort* Bs = smem + 8192 + (t % 3) * 4096;
        half8 a[4], b[4];
#pragma unroll
        for (int mf = 0; mf < 4; mf++)
            a[mf] = __builtin_bit_cast(half8, *(const short8*)(As + (64 * wm + 16 * mf + lr) * 32 + xq));
#pragma unroll
        for (int nf = 0; nf < 4; nf++)
            b[nf] = __builtin_bit_cast(half8, *(const short8*)(Bs + (64 * wn + 16 * nf + lr) * 32 + xq));
        asm volatile("s_waitcnt lgkmcnt(0)" ::: "memory");
        __builtin_amdgcn_sched_barrier(0);

        __builtin_amdgcn_s_setprio(1);
#pragma unroll
        for (int mf = 0; mf < 4; mf++)
#pragma unroll
            for (int nf = 0; nf < 4; nf++)
                acc[mf][nf] = __builtin_amdgcn_mfma_f32_16x16x32_f16(a[mf], b[nf], acc[mf][nf], 0, 0, 0);
        __builtin_amdgcn_s_setprio(0);

        if (t + 1 < nk) {  // transform y(t+1) -> As[(t+1)&1]; implicit vmcnt drains B(t+1)
            half8 z = {};
            half8 tt = *(const half8*)(s_t + coln);  // s_t zero-padded past 600
            half8 a0 = __builtin_elementwise_max(yn0 + tt, z);
            half8 a1 = __builtin_elementwise_max(yn1 + tt, z);
            ushort* Anx = smem + ((t + 1) & 1) * 4096;
            *(short8*)(Anx + r0 * 32 + aslot) = __builtin_bit_cast(short8, a0);
            *(short8*)(Anx + (r0 + 64) * 32 + aslot) = __builtin_bit_cast(short8, a1);
        }
        asm volatile("s_waitcnt lgkmcnt(0)" ::: "memory");  // ds_writes visible pre-barrier
        BARRIER();
    }

    // Epilogue: stats from regs + two 64-row half-tiles through LDS
#pragma unroll
    for (int half = 0; half < 2; half++) {
        if (wm == half) {
#pragma unroll
            for (int nf = 0; nf < 4; nf++) {
                int lcol = 64 * wn + 16 * nf + lr;
                int gn = n0 + lcol;
                float bv = (gn < DIM) ? bias[gn] : 0.f;
                float ps = 0.f, pq = 0.f;
#pragma unroll
                for (int mf = 0; mf < 4; mf++) {
#pragma unroll
                    for (int r = 0; r < 4; r++) {
                        int lrow = 16 * mf + quad * 4 + r;  // 0..63 within half
                        float v = acc[mf][nf][r] + bv;
                        smem[lrow * CT_STRIDE + lcol] = f2h(v);
                        if (m0 + 64 * half + lrow < N_NODES && gn < DIM) { ps += v; pq += v * v; }
                    }
                }
                if (gn < DIM) {
                    atomicAdd(&s_sum[lcol], ps);
                    atomicAdd(&s_sq[lcol], pq);
                }
            }
        }
        __syncthreads();
        // coalesced readback: 64 rows x 32 chunks of 4 fp16 (8B); DIM=300 is 4-aligned
#pragma unroll
        for (int it = 0; it < 8; it++) {
            int idx = tid + it * 256;
            int row = idx >> 5, ch = idx & 31;
            int gm = m0 + 64 * half + row, gcol = n0 + ch * 4;
            if (gm < N_NODES && gcol < DIM) {
                *(uint2*)(hout + (size_t)gm * DIM + gcol) =
                    *(const uint2*)(smem + row * CT_STRIDE + ch * 4);
            }
        }
        __syncthreads();
    }

    if (tid < 128) {
        int gn = n0 + tid;
        if (gn < DIM) {
            atomicAdd(&csum[gn], s_sum[tid]);
            atomicAdd(&csq[gn], s_sq[tid]);
        }
    }
}

// ---------------- BN stats -> per-column scale/shift (+optional fp16 t' = shift/scale) -
__global__ void bn_finalize(const float* __restrict__ sum, const float* __restrict__ sq,
                            const float* __restrict__ g, const float* __restrict__ b,
                            float* __restrict__ scale, float* __restrict__ shift,
                            ushort* __restrict__ th, int n, int npad) {
    int i = blockIdx.x * blockDim.x + threadIdx.x;
    if (i >= n) {
        if (th && i < npad) th[i] = 0;
        return;
    }
    const float invN = 1.0f / (float)N_NODES;
    float m = sum[i] * invN;
    float v = sq[i] * invN - m * m;
    float inv = rsqrtf(v + 1e-5f);
    float sc = g[i] * inv;
    scale[i] = sc;
    shift[i] = b[i] - m * sc;
    if (th) th[i] = f2h((b[i] - m * sc) / sc);  // scale > 0 (g1 = ones)
}

// ---------------- Final output: BN2 of last layer from fp16 h -> fp32 out -------------
__global__ void bn_apply_out(const ushort* __restrict__ h, const float* __restrict__ scale,
                             const float* __restrict__ shift, float* __restrict__ out) {
    int idx = blockIdx.x * blockDim.x + threadIdx.x;  // pair index
    const int PAIRS = DIM / 2;
    if (idx >= N_NODES * PAIRS) return;
    int p = idx % PAIRS;
    uint u = ((const uint*)h)[idx];
    float2 sc = *(const float2*)(scale + 2 * p);
    float2 sh = *(const float2*)(shift + 2 * p);
    float2 o;
    o.x = h2f((ushort)(u & 0xffffu)) * sc.x + sh.x;
    o.y = h2f((ushort)(u >> 16)) * sc.y + sh.y;
    *(float2*)(out + 2 * idx) = o;
}

extern "C" void kernel_launch(void* const* d_in, const int* in_sizes, int n_in,
                              void* d_out, int out_size, void* d_ws, size_t ws_size,
                              hipStream_t stream) {
    const int* x = (const int*)d_in[0];
    const int* ei = (const int*)d_in[1];
    const int* ea = (const int*)d_in[2];
    const float* atom_emb = (const float*)d_in[3];
    const float* bond_emb = (const float*)d_in[4];
    const float* eps = (const float*)d_in[5];
    const float* W1 = (const float*)d_in[6];
    const float* b1 = (const float*)d_in[7];
    const float* g1 = (const float*)d_in[8];
    const float* be1 = (const float*)d_in[9];
    const float* W2 = (const float*)d_in[10];
    const float* b2 = (const float*)d_in[11];
    const float* gamma = (const float*)d_in[12];
    const float* beta = (const float*)d_in[13];
    float* out = (float*)d_out;

    float* ws = (float*)d_ws;
    ushort* h    = (ushort*)ws;                          // N*DIM us = 7,500,000 f
    ushort* A1h  = (ushort*)(ws + 7500000);              // MPAD*KP1 us = 8,007,680 f
    ushort* yh   = (ushort*)(ws + 15507680);             // MPAD*DIM2 us = 15,014,400 f
    ushort* Wt1  = (ushort*)(ws + 30522080);             // NP1*KP1 us = 102,400 f
    ushort* Wt2  = (ushort*)(ws + 30624480);             // NP2*KP2 us = 116,736 f
    ushort* bondh = (ushort*)(ws + 30741216);            // 48*DIM us = 7,200 f
    float* stats = ws + 30748416;                        // 3,600 f
    ushort* t1h  = (ushort*)(ws + 30752016);             // KP2 us = 304 f
    int* rowstart = (int*)(ws + 30752320);               // N+1
    int* deg      = rowstart + 50001;
    int* cursor   = deg + 50000;
    int2* epack   = (int2*)(cursor + 50000 + 1);         // align to 8B
    int* bsum     = (int*)(epack + 250000);              // SCAN_BLOCKS

    float* sum1 = stats;
    float* sq1  = stats + 600;
    float* sum2 = stats + 1200;
    float* sq2  = stats + 1500;
    float* scale1 = stats + 1800;
    float* shift1 = stats + 2400;
    float* scale2 = stats + 3000;
    float* shift2 = stats + 3300;

    const int PAIRS_N = N_NODES * (DIM / 2);

    // CSR build (once; edge_index is layer-invariant)
    hipMemsetAsync(deg, 0, 50000 * sizeof(int), stream);
    deg_count<<<(N_EDGES + 255) / 256, 256, 0, stream>>>(ei, deg);
    block_sums<<<SCAN_BLOCKS, 256, 0, stream>>>(deg, bsum);
    scan_bsums<<<1, 256, 0, stream>>>(bsum);
    write_rowstart<<<SCAN_BLOCKS, 256, 0, stream>>>(deg, bsum, rowstart, cursor);
    csr_fill<<<(N_EDGES + 255) / 256, 256, 0, stream>>>(ei, ea, cursor, epack);

    atom_enc<<<(PAIRS_N + 255) / 256, 256, 0, stream>>>(x, atom_emb, h);
    init_bn<<<(DIM + 255) / 256, 256, 0, stream>>>(scale2, shift2);

    for (int l = 0; l < NL; ++l) {
        hipMemsetAsync(stats, 0, 1800 * sizeof(float), stream);

        bond_conv<<<(48 * (DIM / 2) + 255) / 256, 256, 0, stream>>>(
            bond_emb + (size_t)l * 3 * 16 * DIM, bondh);

        agg_combine<<<(MPAD + 3) / 4, 256, 0, stream>>>(rowstart, epack, bondh,
                                                        h, scale2, shift2, (l > 0) ? 1 : 0,
                                                        eps, l, A1h);

        wt_conv<<<(KP1 * NP1 + 255) / 256, 256, 0, stream>>>(W1 + (size_t)l * DIM * DIM2, Wt1,
                                                             DIM, DIM2, KP1, NP1);

        gemm_mfma<<<(MPAD / 128) * (NP1 / 128), 256, 0, stream>>>(
            A1h, Wt1, b1 + l * DIM2, yh, N_NODES, KP1, DIM2, DIM2, NP1 / 128, sum1, sq1);

        bn_finalize<<<(KP2 + 255) / 256, 256, 0, stream>>>(sum1, sq1, g1 + l * DIM2,
                                                           be1 + l * DIM2, scale1, shift1,
                                                           t1h, DIM2, KP2);

        wt_conv2<<<(KP2 * NP2 + 255) / 256, 256, 0, stream>>>(W2 + (size_t)l * DIM2 * DIM,
                                                              scale1, Wt2);

        gemm2_fused<<<(MPAD / 128) * (NP2 / 128), 256, 0, stream>>>(
            yh, Wt2, t1h, b2 + l * DIM, h, sum2, sq2);

        bn_finalize<<<(DIM + 255) / 256, 256, 0, stream>>>(sum2, sq2, gamma + l * DIM,
                                                           beta + l * DIM, scale2, shift2,
                                                           nullptr, DIM, DIM);
    }

    // final output: BN2 of last layer, no ReLU
    bn_apply_out<<<(PAIRS_N + 255) / 256, 256, 0, stream>>>(h, scale2, shift2, out);
}